// Round 1
// baseline (1098.381 us; speedup 1.0000x reference)
//
#include <hip/hip_runtime.h>
#include <math.h>

#define BB   32
#define TT   12
#define NNODE 325
#define BN   (BB * NNODE)   // 10400
#define EE   96
#define LHH  128
#define HH   64
#define OUTT 12
#define XC   97             // 1 + E channels in x

// ---------------------------------------------------------------------------
// K1: meta[bn][e] = mean_t x[b][t][n][1+e]
// ---------------------------------------------------------------------------
__global__ void meta_kernel(const float* __restrict__ x, float* __restrict__ meta) {
    int idx = blockIdx.x * 256 + threadIdx.x;
    if (idx >= BN * EE) return;
    int e  = idx % EE;
    int bn = idx / EE;
    int b = bn / NNODE, n = bn % NNODE;
    const float* px = x + ((size_t)b * TT * NNODE + n) * XC + 1 + e;
    float s = 0.f;
#pragma unroll
    for (int t = 0; t < TT; ++t) s += px[(size_t)t * NNODE * XC];
    meta[idx] = s * (1.0f / 12.0f);
}

// ---------------------------------------------------------------------------
// K2: stage-1 for the Wh hypernet only: hdnwh[g][bn][l] = relu(meta@wh1 + wh1b)
// grid (BN/16, 4), block 256
// ---------------------------------------------------------------------------
__global__ void stage1_wh_kernel(const float* __restrict__ meta,
                                 const float* __restrict__ wh1,
                                 const float* __restrict__ wh1b,
                                 float* __restrict__ hdnwh) {
    int g = blockIdx.y;
    const float* w1  = wh1 + (size_t)g * EE * LHH;
    const float* w1b = wh1b + g * LHH;
    int row0 = blockIdx.x * 16;
    __shared__ float ms[16][EE];
    for (int i = threadIdx.x; i < 16 * EE; i += 256) {
        int r = i / EE, e = i - r * EE;
        int row = row0 + r;
        ms[r][e] = (row < BN) ? meta[(size_t)row * EE + e] : 0.f;
    }
    __syncthreads();
    int l = threadIdx.x & 127;
    int rbase = (threadIdx.x >> 7) * 8;
    float acc[8] = {0.f,0.f,0.f,0.f,0.f,0.f,0.f,0.f};
    for (int e = 0; e < EE; ++e) {
        float w = w1[(size_t)e * LHH + l];
#pragma unroll
        for (int r = 0; r < 8; ++r) acc[r] += ms[rbase + r][e] * w;
    }
    float bias = w1b[l];
    for (int r = 0; r < 8; ++r) {
        int row = row0 + rbase + r;
        if (row < BN) hdnwh[((size_t)g * BN + row) * LHH + l] = fmaxf(acc[r] + bias, 0.f);
    }
}

// ---------------------------------------------------------------------------
// K3: fused small hypernets (Wx and bias paths), stage1+stage2.
// wxbb[(a*4+g)*BN + bn][k]:  a=0 -> Wx, a=1 -> bb.   grid BN/8, block 256
// ---------------------------------------------------------------------------
__global__ void smallhyper_kernel(const float* __restrict__ meta,
                                  const float* __restrict__ wx1, const float* __restrict__ wx1b,
                                  const float* __restrict__ wx2, const float* __restrict__ wx2b,
                                  const float* __restrict__ b1,  const float* __restrict__ b1b,
                                  const float* __restrict__ b2,  const float* __restrict__ b2b,
                                  float* __restrict__ wxbb) {
    int row0 = blockIdx.x * 8;
    int tid = threadIdx.x;
    __shared__ float ms[8][EE];       // 3 KB
    __shared__ float hd[8][1024];     // 32 KB: [row][(a*4+g)*128 + l]
    for (int i = tid; i < 8 * EE; i += 256) {
        int r = i / EE, e = i - r * EE;
        ms[r][e] = meta[(size_t)(row0 + r) * EE + e];
    }
    __syncthreads();
    // stage 1: 8 combos (a,g) x 128 l, for 8 rows
#pragma unroll
    for (int it = 0; it < 4; ++it) {
        int p = it * 256 + tid;           // 0..1023
        int ag = p >> 7, l = p & 127;
        int a = ag >> 2, g = ag & 3;
        const float* w1p = (a ? b1 : wx1) + (size_t)g * EE * LHH + l;
        float accr[8] = {0.f,0.f,0.f,0.f,0.f,0.f,0.f,0.f};
        for (int e = 0; e < EE; ++e) {
            float w = w1p[(size_t)e * LHH];
#pragma unroll
            for (int rr = 0; rr < 8; ++rr) accr[rr] += ms[rr][e] * w;
        }
        float bias = (a ? b1b : wx1b)[g * LHH + l];
#pragma unroll
        for (int rr = 0; rr < 8; ++rr) hd[rr][ag * 128 + l] = fmaxf(accr[rr] + bias, 0.f);
    }
    __syncthreads();
    // stage 2: (a,g,k): 2*4*64 = 512 outputs per row
#pragma unroll
    for (int it = 0; it < 2; ++it) {
        int q = it * 256 + tid;           // 0..511
        int a = q >> 8, g = (q >> 6) & 3, k = q & 63;
        const float* w2p = (a ? b2 : wx2) + (size_t)g * LHH * HH + k;
        float accr[8] = {0.f,0.f,0.f,0.f,0.f,0.f,0.f,0.f};
        for (int l = 0; l < LHH; ++l) {
            float w = w2p[(size_t)l * HH];
#pragma unroll
            for (int rr = 0; rr < 8; ++rr) accr[rr] += hd[rr][(a * 4 + g) * 128 + l] * w;
        }
        float bias = (a ? b2b : wx2b)[g * HH + k];
#pragma unroll
        for (int rr = 0; rr < 8; ++rr)
            wxbb[((size_t)(a * 4 + g) * BN + row0 + rr) * HH + k] = accr[rr] + bias;
    }
}

// ---------------------------------------------------------------------------
// K4: Wh GEMM for one chunk: whbuf[r][g][j] = hdnwh[g][chunk0+r] @ wh2[g][:,j] + wh2b
// tile 64 rows x 64 cols, K=128 in 4 slices of 32. 64 threads, 8x8 micro.
// grid (64, ceil(cr/64), 4)
// ---------------------------------------------------------------------------
__global__ __launch_bounds__(64, 2) void gemm_wh_kernel(const float* __restrict__ hdnwh,
                                                        const float* __restrict__ wh2,
                                                        const float* __restrict__ wh2b,
                                                        float* __restrict__ whbuf,
                                                        int chunk0, int chunkrows) {
    int g    = blockIdx.z;
    int col0 = blockIdx.x * 64;
    int r0   = blockIdx.y * 64;
    __shared__ float As[32][65];   // [k][r], padded
    __shared__ float Bs[32][64];   // [k][c]
    const float* Ap = hdnwh + ((size_t)g * BN + chunk0 + r0) * LHH;
    const float* Bp = wh2 + (size_t)g * LHH * 4096 + col0;
    int tr = (threadIdx.x >> 3) * 8;   // 0..56
    int tc = (threadIdx.x & 7) * 8;    // 0..56
    float acc[8][8] = {};
    for (int ks = 0; ks < 4; ++ks) {
        int t4 = threadIdx.x * 4;
#pragma unroll
        for (int i = 0; i < 2048; i += 256) {         // A slice: 64 r x 32 k
            int flat = i + t4;
            int r = flat >> 5, kk = flat & 31;
            float4 v = make_float4(0.f, 0.f, 0.f, 0.f);
            if (r0 + r < chunkrows) v = *(const float4*)(Ap + (size_t)r * LHH + ks * 32 + kk);
            As[kk][r] = v.x; As[kk + 1][r] = v.y; As[kk + 2][r] = v.z; As[kk + 3][r] = v.w;
        }
#pragma unroll
        for (int i = 0; i < 2048; i += 256) {         // B slice: 32 k x 64 c
            int flat = i + t4;
            int kk = flat >> 6, c = flat & 63;
            *(float4*)&Bs[kk][c] = *(const float4*)(Bp + (size_t)(ks * 32 + kk) * 4096 + c);
        }
        __syncthreads();
#pragma unroll 8
        for (int kk = 0; kk < 32; ++kk) {
            float4 a0  = *(const float4*)&As[kk][tr];
            float4 a1  = *(const float4*)&As[kk][tr + 4];
            float4 b0  = *(const float4*)&Bs[kk][tc];
            float4 b1v = *(const float4*)&Bs[kk][tc + 4];
            float av[8] = {a0.x, a0.y, a0.z, a0.w, a1.x, a1.y, a1.z, a1.w};
            float bv[8] = {b0.x, b0.y, b0.z, b0.w, b1v.x, b1v.y, b1v.z, b1v.w};
#pragma unroll
            for (int i2 = 0; i2 < 8; ++i2)
#pragma unroll
                for (int j = 0; j < 8; ++j) acc[i2][j] += av[i2] * bv[j];
        }
        __syncthreads();
    }
    float4 biasA = *(const float4*)(wh2b + (size_t)g * 4096 + col0 + tc);
    float4 biasB = *(const float4*)(wh2b + (size_t)g * 4096 + col0 + tc + 4);
    float bv[8] = {biasA.x, biasA.y, biasA.z, biasA.w, biasB.x, biasB.y, biasB.z, biasB.w};
#pragma unroll
    for (int i2 = 0; i2 < 8; ++i2) {
        int rr = r0 + tr + i2;
        if (rr < chunkrows) {
            float* op = whbuf + ((size_t)rr * 4 + g) * 4096 + col0 + tc;
            float4 o0 = make_float4(acc[i2][0] + bv[0], acc[i2][1] + bv[1],
                                    acc[i2][2] + bv[2], acc[i2][3] + bv[3]);
            float4 o1 = make_float4(acc[i2][4] + bv[4], acc[i2][5] + bv[5],
                                    acc[i2][6] + bv[6], acc[i2][7] + bv[7]);
            *(float4*)op = o0;
            *(float4*)(op + 4) = o1;
        }
    }
}

// ---------------------------------------------------------------------------
// K5: per-(b,n) fused LSTM (12 steps) + output head.
// block = 256 threads = (g = tid>>6, k = tid&63). Wh column held in registers.
// grid = chunkrows
// ---------------------------------------------------------------------------
__global__ __launch_bounds__(256) void lstm_head_kernel(const float* __restrict__ whbuf,
                                                        const float* __restrict__ wxbb,
                                                        const float* __restrict__ x,
                                                        const float* __restrict__ fc1,
                                                        const float* __restrict__ fc1b,
                                                        const float* __restrict__ fc2,
                                                        const float* __restrict__ fc2b,
                                                        float* __restrict__ out,
                                                        int chunk0) {
    int r   = blockIdx.x;
    int row = chunk0 + r;
    int b = row / NNODE, n = row - b * NNODE;
    int tid = threadIdx.x;
    int g = tid >> 6, k = tid & 63;

    const float* wp = whbuf + ((size_t)r * 4 + g) * 4096 + k;
    float whcol[64];
#pragma unroll
    for (int h = 0; h < 64; ++h) whcol[h] = wp[(size_t)h * 64];
    float wxv = wxbb[((size_t)g * BN + row) * HH + k];
    float bbv = wxbb[((size_t)(4 + g) * BN + row) * HH + k];

    __shared__ float xts[TT];
    __shared__ float hs[64];
    __shared__ float act[4][64];
    __shared__ float a1[32];
    if (tid < TT) xts[tid] = x[((size_t)b * TT + tid) * NNODE * XC + (size_t)n * XC];
    if (tid < 64) hs[tid] = 0.f;
    float c = 0.f;
    __syncthreads();

    for (int t = 0; t < TT; ++t) {
        float z = wxv * xts[t] + bbv;
#pragma unroll
        for (int h = 0; h < 64; h += 4) {
            float4 hv = *(const float4*)&hs[h];
            z += hv.x * whcol[h] + hv.y * whcol[h + 1] + hv.z * whcol[h + 2] + hv.w * whcol[h + 3];
        }
        float a = (g == 0) ? tanhf(z) : (1.f / (1.f + __expf(-z)));
        act[g][k] = a;
        __syncthreads();
        if (tid < 64) {
            c = act[0][tid] * act[1][tid] + c * act[2][tid];
            hs[tid] = tanhf(c) * act[3][tid];
        }
        __syncthreads();
    }
    // head: relu(h) @ fc1 + b -> relu -> @ fc2 + b
    if (tid < 32) {
        float s = fc1b[tid];
#pragma unroll
        for (int h = 0; h < 64; ++h) s += fmaxf(hs[h], 0.f) * fc1[h * 32 + tid];
        a1[tid] = fmaxf(s, 0.f);
    }
    __syncthreads();
    if (tid < OUTT) {
        float s = fc2b[tid];
#pragma unroll
        for (int j = 0; j < 32; ++j) s += a1[j] * fc2[j * OUTT + tid];
        out[((size_t)b * OUTT + tid) * NNODE + n] = s;
    }
}

// ---------------------------------------------------------------------------
extern "C" void kernel_launch(void* const* d_in, const int* in_sizes, int n_in,
                              void* d_out, int out_size, void* d_ws, size_t ws_size,
                              hipStream_t stream) {
    (void)in_sizes; (void)n_in; (void)out_size;
    const float* x    = (const float*)d_in[0];
    const float* wx1  = (const float*)d_in[1];
    const float* wx1b = (const float*)d_in[2];
    const float* wx2  = (const float*)d_in[3];
    const float* wx2b = (const float*)d_in[4];
    const float* wh1  = (const float*)d_in[5];
    const float* wh1b = (const float*)d_in[6];
    const float* wh2  = (const float*)d_in[7];
    const float* wh2b = (const float*)d_in[8];
    const float* b1   = (const float*)d_in[9];
    const float* b1b  = (const float*)d_in[10];
    const float* b2   = (const float*)d_in[11];
    const float* b2b  = (const float*)d_in[12];
    const float* fc1  = (const float*)d_in[13];
    const float* fc1b = (const float*)d_in[14];
    const float* fc2  = (const float*)d_in[15];
    const float* fc2b = (const float*)d_in[16];
    float* out = (float*)d_out;
    float* ws  = (float*)d_ws;

    float* meta  = ws;                       //   998,400 f
    float* hdnwh = meta + 998400;            // 5,324,800 f
    float* wxbb  = hdnwh + 5324800;          // 5,324,800 f
    float* whbuf = wxbb + 5324800;           // chunk * 16384 f

    const size_t fixedf = 998400 + 5324800 + 5324800;   // 11,648,000 floats
    size_t availf = (ws_size / 4 > fixedf) ? (ws_size / 4 - fixedf) : 0;
    long long ch = (long long)(availf / 16384);
    if (ch > 2048) ch = 2048;
    if (ch < 64)   ch = 64;       // below this ws is unusably small anyway
    int chunk = (int)(ch & ~63LL);

    meta_kernel<<<(BN * EE + 255) / 256, 256, 0, stream>>>(x, meta);
    stage1_wh_kernel<<<dim3(BN / 16, 4), 256, 0, stream>>>(meta, wh1, wh1b, hdnwh);
    smallhyper_kernel<<<BN / 8, 256, 0, stream>>>(meta, wx1, wx1b, wx2, wx2b,
                                                  b1, b1b, b2, b2b, wxbb);
    for (int c0 = 0; c0 < BN; c0 += chunk) {
        int cr = BN - c0;
        if (cr > chunk) cr = chunk;
        gemm_wh_kernel<<<dim3(64, (cr + 63) / 64, 4), 64, 0, stream>>>(
            hdnwh, wh2, wh2b, whbuf, c0, cr);
        lstm_head_kernel<<<cr, 256, 0, stream>>>(whbuf, wxbb, x, fc1, fc1b,
                                                 fc2, fc2b, out, c0);
    }
}

// Round 2
// 669.267 us; speedup vs baseline: 1.6412x; 1.6412x over previous
//
#include <hip/hip_runtime.h>
#include <math.h>

#define BB   32
#define TT   12
#define NNODE 325
#define BN   (BB * NNODE)   // 10400
#define BNP  10496          // BN padded to multiple of 128 for GEMM tiles
#define EE   96
#define LHH  128
#define HH   64
#define OUTT 12
#define XC   97             // 1 + E channels in x
#define KK3  384            // tripled K for bf16 hi/lo split GEMM

typedef __attribute__((ext_vector_type(8))) short short8v;
typedef __attribute__((ext_vector_type(4))) float f32x4;

#define GLOAD16(g, l) __builtin_amdgcn_global_load_lds(                        \
    (const __attribute__((address_space(1))) void*)(g),                        \
    (__attribute__((address_space(3))) void*)(l), 16, 0, 0)

// split f32 into bf16 hi (truncate) and bf16 lo (truncate of residual)
__device__ inline void bf16split(float v, short& hi, short& lo) {
    unsigned u = __float_as_uint(v);
    hi = (short)(u >> 16);
    float fhi = __uint_as_float(u & 0xffff0000u);
    float r = v - fhi;
    lo = (short)(__float_as_uint(r) >> 16);
}

// ---------------------------------------------------------------------------
// K1: meta[bn][e] = mean_t x[b][t][n][1+e]
// ---------------------------------------------------------------------------
__global__ void meta_kernel(const float* __restrict__ x, float* __restrict__ meta) {
    int idx = blockIdx.x * 256 + threadIdx.x;
    if (idx >= BN * EE) return;
    int e  = idx % EE;
    int bn = idx / EE;
    int b = bn / NNODE, n = bn % NNODE;
    const float* px = x + ((size_t)b * TT * NNODE + n) * XC + 1 + e;
    float s = 0.f;
#pragma unroll
    for (int t = 0; t < TT; ++t) s += px[(size_t)t * NNODE * XC];
    meta[idx] = s * (1.0f / 12.0f);
}

// ---------------------------------------------------------------------------
// K2: stage-1 Wh hypernet, emitting bf16 split A' = [hi | hi | lo] (K=384)
// hdnwh2[g][row][384] bf16, rows padded to BNP (tail rows = 0)
// grid (BNP/16, 4), block 256
// ---------------------------------------------------------------------------
__global__ void stage1_wh_kernel(const float* __restrict__ meta,
                                 const float* __restrict__ wh1,
                                 const float* __restrict__ wh1b,
                                 short* __restrict__ hdnwh2) {
    int g = blockIdx.y;
    const float* w1  = wh1 + (size_t)g * EE * LHH;
    const float* w1b = wh1b + g * LHH;
    int row0 = blockIdx.x * 16;
    __shared__ float ms[16][EE];
    for (int i = threadIdx.x; i < 16 * EE; i += 256) {
        int r = i / EE, e = i - r * EE;
        int row = row0 + r;
        ms[r][e] = (row < BN) ? meta[(size_t)row * EE + e] : 0.f;
    }
    __syncthreads();
    int l = threadIdx.x & 127;
    int rbase = (threadIdx.x >> 7) * 8;
    float acc[8] = {0.f,0.f,0.f,0.f,0.f,0.f,0.f,0.f};
    for (int e = 0; e < EE; ++e) {
        float w = w1[(size_t)e * LHH + l];
#pragma unroll
        for (int r = 0; r < 8; ++r) acc[r] += ms[rbase + r][e] * w;
    }
    float bias = w1b[l];
    for (int r = 0; r < 8; ++r) {
        int row = row0 + rbase + r;
        float h = (row < BN) ? fmaxf(acc[r] + bias, 0.f) : 0.f;
        short hi, lo;
        bf16split(h, hi, lo);
        size_t base = ((size_t)g * BNP + row) * KK3 + l;
        hdnwh2[base]       = hi;
        hdnwh2[base + 128] = hi;
        hdnwh2[base + 256] = lo;
    }
}

// ---------------------------------------------------------------------------
// K2b: build B' transposed: b2t[g][col(4096)][384] = [hi | lo | hi] of wh2[g][l][col]
// grid (4096/64, 128/64, 4), block 256
// ---------------------------------------------------------------------------
__global__ void b2t_kernel(const float* __restrict__ wh2, short* __restrict__ b2t) {
    int g = blockIdx.z, l0 = blockIdx.y * 64, c0 = blockIdx.x * 64;
    __shared__ float tile[64][65];
    for (int i = threadIdx.x; i < 64 * 64; i += 256) {
        int rl = i >> 6, cc = i & 63;
        tile[rl][cc] = wh2[(size_t)(g * 128 + l0 + rl) * 4096 + c0 + cc];
    }
    __syncthreads();
    for (int i = threadIdx.x; i < 64 * 64; i += 256) {
        int cl = i >> 6, ll = i & 63;
        float v = tile[ll][cl];
        short hi, lo;
        bf16split(v, hi, lo);
        size_t base = ((size_t)g * 4096 + c0 + cl) * KK3 + l0 + ll;
        b2t[base]       = hi;
        b2t[base + 128] = lo;
        b2t[base + 256] = hi;
    }
}

// ---------------------------------------------------------------------------
// K3: fused small hypernets (Wx and bias paths), stage1+stage2. (unchanged)
// ---------------------------------------------------------------------------
__global__ void smallhyper_kernel(const float* __restrict__ meta,
                                  const float* __restrict__ wx1, const float* __restrict__ wx1b,
                                  const float* __restrict__ wx2, const float* __restrict__ wx2b,
                                  const float* __restrict__ b1,  const float* __restrict__ b1b,
                                  const float* __restrict__ b2,  const float* __restrict__ b2b,
                                  float* __restrict__ wxbb) {
    int row0 = blockIdx.x * 8;
    int tid = threadIdx.x;
    __shared__ float ms[8][EE];
    __shared__ float hd[8][1024];
    for (int i = tid; i < 8 * EE; i += 256) {
        int r = i / EE, e = i - r * EE;
        ms[r][e] = meta[(size_t)(row0 + r) * EE + e];
    }
    __syncthreads();
#pragma unroll
    for (int it = 0; it < 4; ++it) {
        int p = it * 256 + tid;
        int ag = p >> 7, l = p & 127;
        int a = ag >> 2, g = ag & 3;
        const float* w1p = (a ? b1 : wx1) + (size_t)g * EE * LHH + l;
        float accr[8] = {0.f,0.f,0.f,0.f,0.f,0.f,0.f,0.f};
        for (int e = 0; e < EE; ++e) {
            float w = w1p[(size_t)e * LHH];
#pragma unroll
            for (int rr = 0; rr < 8; ++rr) accr[rr] += ms[rr][e] * w;
        }
        float bias = (a ? b1b : wx1b)[g * LHH + l];
#pragma unroll
        for (int rr = 0; rr < 8; ++rr) hd[rr][ag * 128 + l] = fmaxf(accr[rr] + bias, 0.f);
    }
    __syncthreads();
#pragma unroll
    for (int it = 0; it < 2; ++it) {
        int q = it * 256 + tid;
        int a = q >> 8, g = (q >> 6) & 3, k = q & 63;
        const float* w2p = (a ? b2 : wx2) + (size_t)g * LHH * HH + k;
        float accr[8] = {0.f,0.f,0.f,0.f,0.f,0.f,0.f,0.f};
        for (int l = 0; l < LHH; ++l) {
            float w = w2p[(size_t)l * HH];
#pragma unroll
            for (int rr = 0; rr < 8; ++rr) accr[rr] += hd[rr][(a * 4 + g) * 128 + l] * w;
        }
        float bias = (a ? b2b : wx2b)[g * HH + k];
#pragma unroll
        for (int rr = 0; rr < 8; ++rr)
            wxbb[((size_t)(a * 4 + g) * BN + row0 + rr) * HH + k] = accr[rr] + bias;
    }
}

// ---------------------------------------------------------------------------
// K4: bf16-split MFMA GEMM.  C[row][g][col] = A'[g,row,:] . B'[g,:,col] + bias
// 128x128 tile, BK=32, K=384 (12 steps). 256 threads = 4 waves (2x2 of 64x64).
// LDS tiles As/Bt: [128 rows][32 k] bf16, 16B-slot XOR swizzle x(r)=(r&3)^((r>>2)&1)
// applied on the global source at staging (linear LDS dest) and on the ds_read.
// grid (32, ceil(cr/128), 4)
// ---------------------------------------------------------------------------
__global__ __launch_bounds__(256) void gemm_wh_mfma(const short* __restrict__ hdnwh2,
                                                    const short* __restrict__ b2t,
                                                    const float* __restrict__ wh2b,
                                                    float* __restrict__ whbuf,
                                                    int chunk0, int chunkrows) {
    int g    = blockIdx.z;
    int col0 = blockIdx.x * 128;
    int r0   = blockIdx.y * 128;
    __shared__ short As[128 * 32];
    __shared__ short Bt[128 * 32];
    int tid = threadIdx.x;
    int l = tid & 63, w = tid >> 6;

    const short* Ag = hdnwh2 + ((size_t)g * BNP + chunk0 + r0) * KK3;
    const short* Bg = b2t + ((size_t)g * 4096 + col0) * KK3;

    // staging: wave w owns 1KB chunks {2w, 2w+1} of each 8KB tile
    int ch0 = w * 2, ch1 = w * 2 + 1;
    int rloc = l >> 2;                       // row within 16-row chunk
    int sl = l & 3;                          // 16B slot within 64B row
    int xs = (rloc & 3) ^ ((rloc >> 2) & 1); // swizzle bits (dep. on r&7 only)
    int rA0 = ch0 * 16 + rloc, rA1 = ch1 * 16 + rloc;
    const short* srcA0 = Ag + (size_t)rA0 * KK3 + ((sl ^ xs) << 3);
    const short* srcA1 = Ag + (size_t)rA1 * KK3 + ((sl ^ xs) << 3);
    const short* srcB0 = Bg + (size_t)rA0 * KK3 + ((sl ^ xs) << 3);
    const short* srcB1 = Bg + (size_t)rA1 * KK3 + ((sl ^ xs) << 3);
    short* ldsA0 = As + ch0 * 512;           // wave-uniform bases
    short* ldsA1 = As + ch1 * 512;
    short* ldsB0 = Bt + ch0 * 512;
    short* ldsB1 = Bt + ch1 * 512;

    // fragment read addresses (constant across K steps)
    int wr = w >> 1, wc = w & 1;
    int lr = l & 15, hk = l >> 4;
    int xr = (lr & 3) ^ ((lr >> 2) & 1);
    const short* ap[4];
    const short* bp[4];
#pragma unroll
    for (int m = 0; m < 4; ++m) ap[m] = As + (wr * 64 + m * 16 + lr) * 32 + ((hk ^ xr) << 3);
#pragma unroll
    for (int n = 0; n < 4; ++n) bp[n] = Bt + (wc * 64 + n * 16 + lr) * 32 + ((hk ^ xr) << 3);

    f32x4 zero = {0.f, 0.f, 0.f, 0.f};
    f32x4 acc[4][4];
#pragma unroll
    for (int m = 0; m < 4; ++m)
#pragma unroll
        for (int n = 0; n < 4; ++n) acc[m][n] = zero;

    for (int ks = 0; ks < 12; ++ks) {
        int ko = ks * 32;
        GLOAD16(srcA0 + ko, ldsA0);
        GLOAD16(srcA1 + ko, ldsA1);
        GLOAD16(srcB0 + ko, ldsB0);
        GLOAD16(srcB1 + ko, ldsB1);
        __syncthreads();
        short8v a[4], b[4];
#pragma unroll
        for (int m = 0; m < 4; ++m) a[m] = *(const short8v*)ap[m];
#pragma unroll
        for (int n = 0; n < 4; ++n) b[n] = *(const short8v*)bp[n];
#pragma unroll
        for (int m = 0; m < 4; ++m)
#pragma unroll
            for (int n = 0; n < 4; ++n)
                acc[m][n] = __builtin_amdgcn_mfma_f32_16x16x32_bf16(a[m], b[n], acc[m][n], 0, 0, 0);
        __syncthreads();
    }

    float bias[4];
#pragma unroll
    for (int n = 0; n < 4; ++n) bias[n] = wh2b[g * 4096 + col0 + wc * 64 + n * 16 + lr];
#pragma unroll
    for (int m = 0; m < 4; ++m) {
#pragma unroll
        for (int reg = 0; reg < 4; ++reg) {
            int row = r0 + wr * 64 + m * 16 + hk * 4 + reg;
            if (row < chunkrows) {
#pragma unroll
                for (int n = 0; n < 4; ++n) {
                    int col = col0 + wc * 64 + n * 16 + lr;
                    whbuf[((size_t)row * 4 + g) * 4096 + col] = acc[m][n][reg] + bias[n];
                }
            }
        }
    }
}

// ---------------------------------------------------------------------------
// K5: per-(b,n) fused LSTM (12 steps) + output head. (unchanged)
// ---------------------------------------------------------------------------
__global__ __launch_bounds__(256) void lstm_head_kernel(const float* __restrict__ whbuf,
                                                        const float* __restrict__ wxbb,
                                                        const float* __restrict__ x,
                                                        const float* __restrict__ fc1,
                                                        const float* __restrict__ fc1b,
                                                        const float* __restrict__ fc2,
                                                        const float* __restrict__ fc2b,
                                                        float* __restrict__ out,
                                                        int chunk0) {
    int r   = blockIdx.x;
    int row = chunk0 + r;
    int b = row / NNODE, n = row - b * NNODE;
    int tid = threadIdx.x;
    int g = tid >> 6, k = tid & 63;

    const float* wp = whbuf + ((size_t)r * 4 + g) * 4096 + k;
    float whcol[64];
#pragma unroll
    for (int h = 0; h < 64; ++h) whcol[h] = wp[(size_t)h * 64];
    float wxv = wxbb[((size_t)g * BN + row) * HH + k];
    float bbv = wxbb[((size_t)(4 + g) * BN + row) * HH + k];

    __shared__ float xts[TT];
    __shared__ float hs[64];
    __shared__ float act[4][64];
    __shared__ float a1[32];
    if (tid < TT) xts[tid] = x[((size_t)b * TT + tid) * NNODE * XC + (size_t)n * XC];
    if (tid < 64) hs[tid] = 0.f;
    float c = 0.f;
    __syncthreads();

    for (int t = 0; t < TT; ++t) {
        float z = wxv * xts[t] + bbv;
#pragma unroll
        for (int h = 0; h < 64; h += 4) {
            float4 hv = *(const float4*)&hs[h];
            z += hv.x * whcol[h] + hv.y * whcol[h + 1] + hv.z * whcol[h + 2] + hv.w * whcol[h + 3];
        }
        float a = (g == 0) ? tanhf(z) : (1.f / (1.f + __expf(-z)));
        act[g][k] = a;
        __syncthreads();
        if (tid < 64) {
            c = act[0][tid] * act[1][tid] + c * act[2][tid];
            hs[tid] = tanhf(c) * act[3][tid];
        }
        __syncthreads();
    }
    if (tid < 32) {
        float s = fc1b[tid];
#pragma unroll
        for (int h = 0; h < 64; ++h) s += fmaxf(hs[h], 0.f) * fc1[h * 32 + tid];
        a1[tid] = fmaxf(s, 0.f);
    }
    __syncthreads();
    if (tid < OUTT) {
        float s = fc2b[tid];
#pragma unroll
        for (int j = 0; j < 32; ++j) s += a1[j] * fc2[j * OUTT + tid];
        out[((size_t)b * OUTT + tid) * NNODE + n] = s;
    }
}

// ---------------------------------------------------------------------------
extern "C" void kernel_launch(void* const* d_in, const int* in_sizes, int n_in,
                              void* d_out, int out_size, void* d_ws, size_t ws_size,
                              hipStream_t stream) {
    (void)in_sizes; (void)n_in; (void)out_size;
    const float* x    = (const float*)d_in[0];
    const float* wx1  = (const float*)d_in[1];
    const float* wx1b = (const float*)d_in[2];
    const float* wx2  = (const float*)d_in[3];
    const float* wx2b = (const float*)d_in[4];
    const float* wh1  = (const float*)d_in[5];
    const float* wh1b = (const float*)d_in[6];
    const float* wh2  = (const float*)d_in[7];
    const float* wh2b = (const float*)d_in[8];
    const float* b1   = (const float*)d_in[9];
    const float* b1b  = (const float*)d_in[10];
    const float* b2   = (const float*)d_in[11];
    const float* b2b  = (const float*)d_in[12];
    const float* fc1  = (const float*)d_in[13];
    const float* fc1b = (const float*)d_in[14];
    const float* fc2  = (const float*)d_in[15];
    const float* fc2b = (const float*)d_in[16];
    float* out = (float*)d_out;
    float* ws  = (float*)d_ws;

    float* meta   = ws;                                  //   998,400 f
    float* wxbb   = meta + 998400;                       // 5,324,800 f
    short* hdnwh2 = (short*)(wxbb + 5324800);            // 4*BNP*384 = 16,121,856 sh
    short* b2t    = hdnwh2 + (size_t)4 * BNP * KK3;      // 4*4096*384 = 6,291,456 sh
    float* whbuf  = (float*)(b2t + (size_t)4 * 4096 * KK3);

    const size_t fixedB = 998400ull * 4 + 5324800ull * 4
                        + ((size_t)4 * BNP * KK3 + (size_t)4 * 4096 * KK3) * 2;
    size_t availB = (ws_size > fixedB) ? (ws_size - fixedB) : 0;
    long long ch = (long long)(availB / (16384 * 4));
    if (ch > 2048) ch = 2048;
    if (ch < 128)  ch = 128;
    int chunk = (int)(ch & ~127LL);

    meta_kernel<<<(BN * EE + 255) / 256, 256, 0, stream>>>(x, meta);
    stage1_wh_kernel<<<dim3(BNP / 16, 4), 256, 0, stream>>>(meta, wh1, wh1b, hdnwh2);
    b2t_kernel<<<dim3(64, 2, 4), 256, 0, stream>>>(wh2, b2t);
    smallhyper_kernel<<<BN / 8, 256, 0, stream>>>(meta, wx1, wx1b, wx2, wx2b,
                                                  b1, b1b, b2, b2b, wxbb);
    for (int c0 = 0; c0 < BN; c0 += chunk) {
        int cr = BN - c0;
        if (cr > chunk) cr = chunk;
        gemm_wh_mfma<<<dim3(32, (cr + 127) / 128, 4), 256, 0, stream>>>(
            hdnwh2, b2t, wh2b, whbuf, c0, cr);
        lstm_head_kernel<<<cr, 256, 0, stream>>>(whbuf, wxbb, x, fc1, fc1b,
                                                 fc2, fc2b, out, c0);
    }
}

// Round 3
// 438.048 us; speedup vs baseline: 2.5074x; 1.5278x over previous
//
#include <hip/hip_runtime.h>
#include <hip/hip_fp16.h>
#include <math.h>

#define BB   32
#define TT   12
#define NNODE 325
#define BN   (BB * NNODE)   // 10400
#define BNP  10496          // BN padded to multiple of 128
#define EE   96
#define LHH  128
#define HH   64
#define OUTT 12
#define XC   97             // 1 + E channels in x

typedef _Float16 f16;
typedef __attribute__((ext_vector_type(8))) _Float16 f16x8;
typedef __attribute__((ext_vector_type(4))) float f32x4;

#define GLOAD16(g, l) __builtin_amdgcn_global_load_lds(                        \
    (const __attribute__((address_space(1))) void*)(g),                        \
    (__attribute__((address_space(3))) void*)(l), 16, 0, 0)

// ---------------------------------------------------------------------------
// K1: meta2[row][e] = fp16(mean_t x[b][t][n][1+e]); pad rows (>=BN) zeroed
// ---------------------------------------------------------------------------
__global__ void meta2_kernel(const float* __restrict__ x, f16* __restrict__ meta2) {
    int idx = blockIdx.x * 256 + threadIdx.x;
    if (idx >= BNP * EE) return;
    int e = idx % EE, row = idx / EE;
    float s = 0.f;
    if (row < BN) {
        int b = row / NNODE, n = row - b * NNODE;
        const float* px = x + ((size_t)b * TT * NNODE + n) * XC + 1 + e;
#pragma unroll
        for (int t = 0; t < TT; ++t) s += px[(size_t)t * NNODE * XC];
        s *= (1.0f / 12.0f);
    }
    meta2[idx] = (f16)s;
}

// ---------------------------------------------------------------------------
// K2: prep: B1t[1536][96] fp16 (stacked stage-1 weights, transposed),
//           bias1[1536] f32, b2s[8][64][128] fp16, bias2s[8][64] f32
// ---------------------------------------------------------------------------
__global__ void prep_kernel(const float* __restrict__ wx1, const float* __restrict__ wx1b,
                            const float* __restrict__ wx2, const float* __restrict__ wx2b,
                            const float* __restrict__ wh1, const float* __restrict__ wh1b,
                            const float* __restrict__ b1,  const float* __restrict__ b1b,
                            const float* __restrict__ b2,  const float* __restrict__ b2b,
                            f16* __restrict__ B1t, float* __restrict__ bias1,
                            f16* __restrict__ b2s, float* __restrict__ bias2s) {
    int idx = blockIdx.x * 256 + threadIdx.x;
    if (idx < 147456) {                       // B1t[c][k] = w1[net][g][k][l]
        int c = idx / 96, k = idx - c * 96;
        int net = c >> 9, g = (c >> 7) & 3, l = c & 127;
        const float* w = (net == 0) ? wx1 : ((net == 1) ? wh1 : b1);
        B1t[idx] = (f16)w[(size_t)g * 96 * 128 + k * 128 + l];
        return;
    }
    idx -= 147456;
    if (idx < 1536) {                         // bias1[c]
        int net = idx >> 9, g = (idx >> 7) & 3, l = idx & 127;
        const float* wb = (net == 0) ? wx1b : ((net == 1) ? wh1b : b1b);
        bias1[idx] = wb[g * 128 + l];
        return;
    }
    idx -= 1536;
    if (idx < 65536) {                        // b2s[combo][cc][k] = w2[a][g][k][cc]
        int combo = idx >> 13, rem = idx & 8191, cc = rem >> 7, k = rem & 127;
        int a = combo >> 2, g = combo & 3;
        const float* w = a ? b2 : wx2;
        b2s[idx] = (f16)w[(size_t)g * 8192 + k * 64 + cc];
        return;
    }
    idx -= 65536;
    if (idx < 512) {                          // bias2s[combo][cc]
        int combo = idx >> 6, cc = idx & 63;
        int a = combo >> 2, g = combo & 3;
        bias2s[idx] = (a ? b2b : wx2b)[g * 64 + cc];
    }
}

// ---------------------------------------------------------------------------
// K3: b2t[g][col][k] = fp16(wh2[g][k][col])  — transposed via LDS tiles
// grid (4096/64, 128/64, 4), block 256
// ---------------------------------------------------------------------------
__global__ void b2t_kernel(const float* __restrict__ wh2, f16* __restrict__ b2t) {
    int g = blockIdx.z, l0 = blockIdx.y * 64, c0 = blockIdx.x * 64;
    __shared__ float tile[64][65];
    for (int i = threadIdx.x; i < 64 * 64; i += 256) {
        int rl = i >> 6, cc = i & 63;
        tile[rl][cc] = wh2[(size_t)(g * 128 + l0 + rl) * 4096 + c0 + cc];
    }
    __syncthreads();
    for (int i = threadIdx.x; i < 64 * 64; i += 256) {
        int cl = i >> 6, ll = i & 63;
        b2t[((size_t)g * 4096 + c0 + cl) * 128 + l0 + ll] = (f16)tile[ll][cl];
    }
}

// ---------------------------------------------------------------------------
// K4: stage-1 GEMM: hdn_all[row][c] = fp16(relu(meta2[row,:] . B1t[c,:] + bias1[c]))
// (BNP x 96) @ (96 x 1536). 128x128 tile, BK=32, 3 K-steps. grid (12, BNP/128)
// ---------------------------------------------------------------------------
__global__ __launch_bounds__(256) void stage1_gemm(const f16* __restrict__ meta2,
                                                   const f16* __restrict__ B1t,
                                                   const float* __restrict__ bias1,
                                                   f16* __restrict__ hdn_all) {
    int c0 = blockIdx.x * 128, r0 = blockIdx.y * 128;
    __shared__ f16 As[128 * 32];
    __shared__ f16 Bs[128 * 32];
    int tid = threadIdx.x, l = tid & 63, w = tid >> 6;
    const f16* Ag = meta2 + (size_t)r0 * 96;
    const f16* Bg = B1t + (size_t)c0 * 96;
    int ch0 = w * 2, ch1 = ch0 + 1;
    int rloc = l >> 2, sl = l & 3;
    int xs = (rloc & 3) ^ ((rloc >> 2) & 1);
    int slx = (sl ^ xs) << 3;
    int rA0 = ch0 * 16 + rloc, rA1 = ch1 * 16 + rloc;
    const f16* srcA0 = Ag + (size_t)rA0 * 96 + slx;
    const f16* srcA1 = Ag + (size_t)rA1 * 96 + slx;
    const f16* srcB0 = Bg + (size_t)rA0 * 96 + slx;
    const f16* srcB1 = Bg + (size_t)rA1 * 96 + slx;
    f16* ldsA0 = As + ch0 * 512; f16* ldsA1 = As + ch1 * 512;
    f16* ldsB0 = Bs + ch0 * 512; f16* ldsB1 = Bs + ch1 * 512;

    int wr = w >> 1, wc = w & 1, lr = l & 15, hk = l >> 4;
    int xr = (lr & 3) ^ ((lr >> 2) & 1);
    const f16 *ap[4], *bp[4];
#pragma unroll
    for (int m = 0; m < 4; ++m) ap[m] = As + (wr * 64 + m * 16 + lr) * 32 + ((hk ^ xr) << 3);
#pragma unroll
    for (int n = 0; n < 4; ++n) bp[n] = Bs + (wc * 64 + n * 16 + lr) * 32 + ((hk ^ xr) << 3);

    f32x4 acc[4][4];
#pragma unroll
    for (int m = 0; m < 4; ++m)
#pragma unroll
        for (int n = 0; n < 4; ++n) acc[m][n] = (f32x4){0.f, 0.f, 0.f, 0.f};

    for (int ks = 0; ks < 3; ++ks) {
        int ko = ks * 32;
        GLOAD16(srcA0 + ko, ldsA0);
        GLOAD16(srcA1 + ko, ldsA1);
        GLOAD16(srcB0 + ko, ldsB0);
        GLOAD16(srcB1 + ko, ldsB1);
        __syncthreads();
        f16x8 a[4], b[4];
#pragma unroll
        for (int m = 0; m < 4; ++m) a[m] = *(const f16x8*)ap[m];
#pragma unroll
        for (int n = 0; n < 4; ++n) b[n] = *(const f16x8*)bp[n];
#pragma unroll
        for (int m = 0; m < 4; ++m)
#pragma unroll
            for (int n = 0; n < 4; ++n)
                acc[m][n] = __builtin_amdgcn_mfma_f32_16x16x32_f16(a[m], b[n], acc[m][n], 0, 0, 0);
        __syncthreads();
    }
    float bias[4];
#pragma unroll
    for (int n = 0; n < 4; ++n) bias[n] = bias1[c0 + wc * 64 + n * 16 + lr];
#pragma unroll
    for (int m = 0; m < 4; ++m)
#pragma unroll
        for (int reg = 0; reg < 4; ++reg) {
            int row = r0 + wr * 64 + m * 16 + hk * 4 + reg;
#pragma unroll
            for (int n = 0; n < 4; ++n) {
                int col = c0 + wc * 64 + n * 16 + lr;
                hdn_all[(size_t)row * 1536 + col] = (f16)fmaxf(acc[m][n][reg] + bias[n], 0.f);
            }
        }
}

// ---------------------------------------------------------------------------
// K5: Wh GEMM fp16: whbuf[row][g][col] = fp16(hdn_all[row, wh-block g] . b2t[g,col,:] + wh2b)
// 128x128 tile, K=128 (4 steps). grid (32, ceil(cr/128), 4)
// ---------------------------------------------------------------------------
__global__ __launch_bounds__(256) void gemm_wh_mfma(const f16* __restrict__ hdn_all,
                                                    const f16* __restrict__ b2t,
                                                    const float* __restrict__ wh2b,
                                                    f16* __restrict__ whbuf,
                                                    int chunk0, int chunkrows) {
    int g = blockIdx.z, col0 = blockIdx.x * 128, r0 = blockIdx.y * 128;
    __shared__ f16 As[128 * 32];
    __shared__ f16 Bt[128 * 32];
    int tid = threadIdx.x, l = tid & 63, w = tid >> 6;
    const f16* Ag = hdn_all + (size_t)(chunk0 + r0) * 1536 + 512 + g * 128;
    const f16* Bg = b2t + ((size_t)g * 4096 + col0) * 128;
    int ch0 = w * 2, ch1 = ch0 + 1;
    int rloc = l >> 2, sl = l & 3;
    int xs = (rloc & 3) ^ ((rloc >> 2) & 1);
    int slx = (sl ^ xs) << 3;
    int rA0 = ch0 * 16 + rloc, rA1 = ch1 * 16 + rloc;
    const f16* srcA0 = Ag + (size_t)rA0 * 1536 + slx;
    const f16* srcA1 = Ag + (size_t)rA1 * 1536 + slx;
    const f16* srcB0 = Bg + (size_t)rA0 * 128 + slx;
    const f16* srcB1 = Bg + (size_t)rA1 * 128 + slx;
    f16* ldsA0 = As + ch0 * 512; f16* ldsA1 = As + ch1 * 512;
    f16* ldsB0 = Bt + ch0 * 512; f16* ldsB1 = Bt + ch1 * 512;

    int wr = w >> 1, wc = w & 1, lr = l & 15, hk = l >> 4;
    int xr = (lr & 3) ^ ((lr >> 2) & 1);
    const f16 *ap[4], *bp[4];
#pragma unroll
    for (int m = 0; m < 4; ++m) ap[m] = As + (wr * 64 + m * 16 + lr) * 32 + ((hk ^ xr) << 3);
#pragma unroll
    for (int n = 0; n < 4; ++n) bp[n] = Bt + (wc * 64 + n * 16 + lr) * 32 + ((hk ^ xr) << 3);

    f32x4 acc[4][4];
#pragma unroll
    for (int m = 0; m < 4; ++m)
#pragma unroll
        for (int n = 0; n < 4; ++n) acc[m][n] = (f32x4){0.f, 0.f, 0.f, 0.f};

    for (int ks = 0; ks < 4; ++ks) {
        int ko = ks * 32;
        GLOAD16(srcA0 + ko, ldsA0);
        GLOAD16(srcA1 + ko, ldsA1);
        GLOAD16(srcB0 + ko, ldsB0);
        GLOAD16(srcB1 + ko, ldsB1);
        __syncthreads();
        f16x8 a[4], b[4];
#pragma unroll
        for (int m = 0; m < 4; ++m) a[m] = *(const f16x8*)ap[m];
#pragma unroll
        for (int n = 0; n < 4; ++n) b[n] = *(const f16x8*)bp[n];
#pragma unroll
        for (int m = 0; m < 4; ++m)
#pragma unroll
            for (int n = 0; n < 4; ++n)
                acc[m][n] = __builtin_amdgcn_mfma_f32_16x16x32_f16(a[m], b[n], acc[m][n], 0, 0, 0);
        __syncthreads();
    }
    float bias[4];
#pragma unroll
    for (int n = 0; n < 4; ++n) bias[n] = wh2b[g * 4096 + col0 + wc * 64 + n * 16 + lr];
#pragma unroll
    for (int m = 0; m < 4; ++m)
#pragma unroll
        for (int reg = 0; reg < 4; ++reg) {
            int row = r0 + wr * 64 + m * 16 + hk * 4 + reg;
            if (row < chunkrows) {
#pragma unroll
                for (int n = 0; n < 4; ++n) {
                    int col = col0 + wc * 64 + n * 16 + lr;
                    whbuf[((size_t)row * 4 + g) * 4096 + col] = (f16)(acc[m][n][reg] + bias[n]);
                }
            }
        }
}

// ---------------------------------------------------------------------------
// K6: batched small stage-2 GEMMs: wxbb[combo][row][64], combo = a*4+g
// (BNP x 128) @ (128 x 64) per combo. Tile 128x64, 4 waves (32 rows each).
// grid (BNP/128, 8)
// ---------------------------------------------------------------------------
__global__ __launch_bounds__(256) void stage2s_gemm(const f16* __restrict__ hdn_all,
                                                    const f16* __restrict__ b2s,
                                                    const float* __restrict__ bias2s,
                                                    float* __restrict__ wxbb) {
    int combo = blockIdx.y, r0 = blockIdx.x * 128;
    int a = combo >> 2, g = combo & 3;
    int aoff = (a ? 1024 : 0) + g * 128;
    __shared__ f16 As[128 * 32];
    __shared__ f16 Bs[64 * 32];
    int tid = threadIdx.x, l = tid & 63, w = tid >> 6;
    const f16* Ag = hdn_all + (size_t)r0 * 1536 + aoff;
    const f16* Bg = b2s + (size_t)combo * 8192;
    int ch0 = w * 2, ch1 = ch0 + 1;
    int rloc = l >> 2, sl = l & 3;
    int xs = (rloc & 3) ^ ((rloc >> 2) & 1);
    int slx = (sl ^ xs) << 3;
    int rA0 = ch0 * 16 + rloc, rA1 = ch1 * 16 + rloc;
    int rB  = w * 16 + rloc;
    const f16* srcA0 = Ag + (size_t)rA0 * 1536 + slx;
    const f16* srcA1 = Ag + (size_t)rA1 * 1536 + slx;
    const f16* srcB  = Bg + (size_t)rB * 128 + slx;
    f16* ldsA0 = As + ch0 * 512; f16* ldsA1 = As + ch1 * 512;
    f16* ldsB  = Bs + w * 512;

    int lr = l & 15, hk = l >> 4;
    int xr = (lr & 3) ^ ((lr >> 2) & 1);
    const f16 *ap[2], *bp[4];
#pragma unroll
    for (int m = 0; m < 2; ++m) ap[m] = As + (w * 32 + m * 16 + lr) * 32 + ((hk ^ xr) << 3);
#pragma unroll
    for (int n = 0; n < 4; ++n) bp[n] = Bs + (n * 16 + lr) * 32 + ((hk ^ xr) << 3);

    f32x4 acc[2][4];
#pragma unroll
    for (int m = 0; m < 2; ++m)
#pragma unroll
        for (int n = 0; n < 4; ++n) acc[m][n] = (f32x4){0.f, 0.f, 0.f, 0.f};

    for (int ks = 0; ks < 4; ++ks) {
        int ko = ks * 32;
        GLOAD16(srcA0 + ko, ldsA0);
        GLOAD16(srcA1 + ko, ldsA1);
        GLOAD16(srcB + ko, ldsB);
        __syncthreads();
        f16x8 av[2], bv[4];
#pragma unroll
        for (int m = 0; m < 2; ++m) av[m] = *(const f16x8*)ap[m];
#pragma unroll
        for (int n = 0; n < 4; ++n) bv[n] = *(const f16x8*)bp[n];
#pragma unroll
        for (int m = 0; m < 2; ++m)
#pragma unroll
            for (int n = 0; n < 4; ++n)
                acc[m][n] = __builtin_amdgcn_mfma_f32_16x16x32_f16(av[m], bv[n], acc[m][n], 0, 0, 0);
        __syncthreads();
    }
    float bias[4];
#pragma unroll
    for (int n = 0; n < 4; ++n) bias[n] = bias2s[combo * 64 + n * 16 + lr];
#pragma unroll
    for (int m = 0; m < 2; ++m)
#pragma unroll
        for (int reg = 0; reg < 4; ++reg) {
            int row = r0 + w * 32 + m * 16 + hk * 4 + reg;
            if (row < BN) {
#pragma unroll
                for (int n = 0; n < 4; ++n) {
                    int col = n * 16 + lr;
                    wxbb[((size_t)combo * BN + row) * 64 + col] = acc[m][n][reg] + bias[n];
                }
            }
        }
}

// ---------------------------------------------------------------------------
// K7: per-(b,n) fused LSTM (12 steps) + output head. whbuf is fp16.
// ---------------------------------------------------------------------------
__global__ __launch_bounds__(256) void lstm_head_kernel(const f16* __restrict__ whbuf,
                                                        const float* __restrict__ wxbb,
                                                        const float* __restrict__ x,
                                                        const float* __restrict__ fc1,
                                                        const float* __restrict__ fc1b,
                                                        const float* __restrict__ fc2,
                                                        const float* __restrict__ fc2b,
                                                        float* __restrict__ out,
                                                        int chunk0) {
    int r   = blockIdx.x;
    int row = chunk0 + r;
    int b = row / NNODE, n = row - b * NNODE;
    int tid = threadIdx.x;
    int g = tid >> 6, k = tid & 63;

    const f16* wp = whbuf + ((size_t)r * 4 + g) * 4096 + k;
    float whcol[64];
#pragma unroll
    for (int h = 0; h < 64; ++h) whcol[h] = (float)wp[(size_t)h * 64];
    float wxv = wxbb[((size_t)g * BN + row) * HH + k];
    float bbv = wxbb[((size_t)(4 + g) * BN + row) * HH + k];

    __shared__ float xts[TT];
    __shared__ float hs[64];
    __shared__ float act[4][64];
    __shared__ float a1[32];
    if (tid < TT) xts[tid] = x[((size_t)b * TT + tid) * NNODE * XC + (size_t)n * XC];
    if (tid < 64) hs[tid] = 0.f;
    float c = 0.f;
    __syncthreads();

    for (int t = 0; t < TT; ++t) {
        float z = wxv * xts[t] + bbv;
#pragma unroll
        for (int h = 0; h < 64; h += 4) {
            float4 hv = *(const float4*)&hs[h];
            z += hv.x * whcol[h] + hv.y * whcol[h + 1] + hv.z * whcol[h + 2] + hv.w * whcol[h + 3];
        }
        float av = (g == 0) ? tanhf(z) : (1.f / (1.f + __expf(-z)));
        act[g][k] = av;
        __syncthreads();
        if (tid < 64) {
            c = act[0][tid] * act[1][tid] + c * act[2][tid];
            hs[tid] = tanhf(c) * act[3][tid];
        }
        __syncthreads();
    }
    if (tid < 32) {
        float s = fc1b[tid];
#pragma unroll
        for (int h = 0; h < 64; ++h) s += fmaxf(hs[h], 0.f) * fc1[h * 32 + tid];
        a1[tid] = fmaxf(s, 0.f);
    }
    __syncthreads();
    if (tid < OUTT) {
        float s = fc2b[tid];
#pragma unroll
        for (int j = 0; j < 32; ++j) s += a1[j] * fc2[j * OUTT + tid];
        out[((size_t)b * OUTT + tid) * NNODE + n] = s;
    }
}

// ---------------------------------------------------------------------------
extern "C" void kernel_launch(void* const* d_in, const int* in_sizes, int n_in,
                              void* d_out, int out_size, void* d_ws, size_t ws_size,
                              hipStream_t stream) {
    (void)in_sizes; (void)n_in; (void)out_size;
    const float* x    = (const float*)d_in[0];
    const float* wx1  = (const float*)d_in[1];
    const float* wx1b = (const float*)d_in[2];
    const float* wx2  = (const float*)d_in[3];
    const float* wx2b = (const float*)d_in[4];
    const float* wh1  = (const float*)d_in[5];
    const float* wh1b = (const float*)d_in[6];
    const float* wh2  = (const float*)d_in[7];
    const float* wh2b = (const float*)d_in[8];
    const float* b1   = (const float*)d_in[9];
    const float* b1b  = (const float*)d_in[10];
    const float* b2   = (const float*)d_in[11];
    const float* b2b  = (const float*)d_in[12];
    const float* fc1  = (const float*)d_in[13];
    const float* fc1b = (const float*)d_in[14];
    const float* fc2  = (const float*)d_in[15];
    const float* fc2b = (const float*)d_in[16];
    float* out = (float*)d_out;
    float* ws  = (float*)d_ws;

    float* bias1  = ws;                      // 1,536 f
    float* bias2s = bias1 + 1536;            // 512 f
    float* wxbb   = bias2s + 512;            // 5,324,800 f
    f16* meta2    = (f16*)(wxbb + 5324800);  // BNP*96
    f16* B1t      = meta2 + (size_t)BNP * 96;        // 147,456
    f16* hdn_all  = B1t + 147456;                    // BNP*1536
    f16* b2t      = hdn_all + (size_t)BNP * 1536;    // 4*4096*128
    f16* b2s      = b2t + (size_t)4 * 4096 * 128;    // 65,536
    f16* whbuf    = b2s + 65536;                     // chunk*16384

    const size_t fixedB = (size_t)(1536 + 512 + 5324800) * 4
        + ((size_t)BNP * 96 + 147456 + (size_t)BNP * 1536 + (size_t)4 * 4096 * 128 + 65536) * 2;
    size_t availB = (ws_size > fixedB) ? (ws_size - fixedB) : 0;
    long long ch = (long long)(availB / (16384 * 2));
    if (ch > 2048) ch = 2048;
    if (ch < 128)  ch = 128;
    int chunk = (int)(ch & ~127LL);

    meta2_kernel<<<(BNP * EE + 255) / 256, 256, 0, stream>>>(x, meta2);
    prep_kernel<<<840, 256, 0, stream>>>(wx1, wx1b, wx2, wx2b, wh1, wh1b,
                                         b1, b1b, b2, b2b, B1t, bias1, b2s, bias2s);
    b2t_kernel<<<dim3(64, 2, 4), 256, 0, stream>>>(wh2, b2t);
    stage1_gemm<<<dim3(12, BNP / 128), 256, 0, stream>>>(meta2, B1t, bias1, hdn_all);
    stage2s_gemm<<<dim3(BNP / 128, 8), 256, 0, stream>>>(hdn_all, b2s, bias2s, wxbb);
    for (int c0 = 0; c0 < BN; c0 += chunk) {
        int cr = BN - c0;
        if (cr > chunk) cr = chunk;
        gemm_wh_mfma<<<dim3(32, (cr + 127) / 128, 4), 256, 0, stream>>>(
            hdn_all, b2t, wh2b, whbuf, c0, cr);
        lstm_head_kernel<<<cr, 256, 0, stream>>>(whbuf, wxbb, x, fc1, fc1b,
                                                 fc2, fc2b, out, c0);
    }
}

// Round 4
// 405.808 us; speedup vs baseline: 2.7066x; 1.0794x over previous
//
#include <hip/hip_runtime.h>
#include <hip/hip_fp16.h>
#include <math.h>

#define BB   32
#define TT   12
#define NNODE 325
#define BN   (BB * NNODE)   // 10400
#define BNP  10496          // BN padded to multiple of 128
#define EE   96
#define LHH  128
#define HH   64
#define OUTT 12
#define XC   97             // 1 + E channels in x

typedef _Float16 f16;
typedef __attribute__((ext_vector_type(8))) _Float16 f16x8;
typedef __attribute__((ext_vector_type(4))) float f32x4;

#define GLOAD16(g, l) __builtin_amdgcn_global_load_lds(                        \
    (const __attribute__((address_space(1))) void*)(g),                        \
    (__attribute__((address_space(3))) void*)(l), 16, 0, 0)

// whbuf column permutation: original col c = h*64+k  ->  col' = (h>>3)*512 + k*8 + (h&7)
// (so whbuf layout per (row,gate) is [j=h>>3][k][e=h&7] -> lstm reads contiguous f16x8)
__device__ __host__ inline int wh_perm(int c) {
    return ((c >> 9) << 9) + ((c & 63) << 3) + ((c >> 6) & 7);
}
__device__ inline int wh_perm_inv(int p) {
    int j = p >> 9, k = (p >> 3) & 63, e = p & 7;
    return (j * 8 + e) * 64 + k;
}

// ---------------------------------------------------------------------------
// K1: meta2[row][e] = fp16(mean_t x[b][t][n][1+e]); pad rows (>=BN) zeroed
// ---------------------------------------------------------------------------
__global__ void meta2_kernel(const float* __restrict__ x, f16* __restrict__ meta2) {
    int idx = blockIdx.x * 256 + threadIdx.x;
    if (idx >= BNP * EE) return;
    int e = idx % EE, row = idx / EE;
    float s = 0.f;
    if (row < BN) {
        int b = row / NNODE, n = row - b * NNODE;
        const float* px = x + ((size_t)b * TT * NNODE + n) * XC + 1 + e;
#pragma unroll
        for (int t = 0; t < TT; ++t) s += px[(size_t)t * NNODE * XC];
        s *= (1.0f / 12.0f);
    }
    meta2[idx] = (f16)s;
}

// ---------------------------------------------------------------------------
// K2: prep: B1t[1536][96] fp16 (stacked stage-1 weights, transposed),
//           bias1[1536] f32, b2s[8][64][128] fp16, bias2s[8][64] f32
// ---------------------------------------------------------------------------
__global__ void prep_kernel(const float* __restrict__ wx1, const float* __restrict__ wx1b,
                            const float* __restrict__ wx2, const float* __restrict__ wx2b,
                            const float* __restrict__ wh1, const float* __restrict__ wh1b,
                            const float* __restrict__ b1,  const float* __restrict__ b1b,
                            const float* __restrict__ b2,  const float* __restrict__ b2b,
                            f16* __restrict__ B1t, float* __restrict__ bias1,
                            f16* __restrict__ b2s, float* __restrict__ bias2s) {
    int idx = blockIdx.x * 256 + threadIdx.x;
    if (idx < 147456) {                       // B1t[c][k] = w1[net][g][k][l]
        int c = idx / 96, k = idx - c * 96;
        int net = c >> 9, g = (c >> 7) & 3, l = c & 127;
        const float* w = (net == 0) ? wx1 : ((net == 1) ? wh1 : b1);
        B1t[idx] = (f16)w[(size_t)g * 96 * 128 + k * 128 + l];
        return;
    }
    idx -= 147456;
    if (idx < 1536) {                         // bias1[c]
        int net = idx >> 9, g = (idx >> 7) & 3, l = idx & 127;
        const float* wb = (net == 0) ? wx1b : ((net == 1) ? wh1b : b1b);
        bias1[idx] = wb[g * 128 + l];
        return;
    }
    idx -= 1536;
    if (idx < 65536) {                        // b2s[combo][cc][k] = w2[a][g][k][cc]
        int combo = idx >> 13, rem = idx & 8191, cc = rem >> 7, k = rem & 127;
        int a = combo >> 2, g = combo & 3;
        const float* w = a ? b2 : wx2;
        b2s[idx] = (f16)w[(size_t)g * 8192 + k * 64 + cc];
        return;
    }
    idx -= 65536;
    if (idx < 512) {                          // bias2s[combo][cc]
        int combo = idx >> 6, cc = idx & 63;
        int a = combo >> 2, g = combo & 3;
        bias2s[idx] = (a ? b2b : wx2b)[g * 64 + cc];
    }
}

// ---------------------------------------------------------------------------
// K3: b2t[g][wh_perm(col)][k] = fp16(wh2[g][k][col])
// grid (4096/64, 128/64, 4), block 256
// ---------------------------------------------------------------------------
__global__ void b2t_kernel(const float* __restrict__ wh2, f16* __restrict__ b2t) {
    int g = blockIdx.z, l0 = blockIdx.y * 64, c0 = blockIdx.x * 64;
    __shared__ float tile[64][65];
    for (int i = threadIdx.x; i < 64 * 64; i += 256) {
        int rl = i >> 6, cc = i & 63;
        tile[rl][cc] = wh2[(size_t)(g * 128 + l0 + rl) * 4096 + c0 + cc];
    }
    __syncthreads();
    for (int i = threadIdx.x; i < 64 * 64; i += 256) {
        int cl = i >> 6, ll = i & 63;
        int colp = wh_perm(c0 + cl);
        b2t[((size_t)g * 4096 + colp) * 128 + l0 + ll] = (f16)tile[ll][cl];
    }
}

// ---------------------------------------------------------------------------
// K4: stage-1 GEMM: hdn_all[row][c] = fp16(relu(meta2[row,:] . B1t[c,:] + bias1[c]))
// (BNP x 96) @ (96 x 1536). 128x128 tile, BK=32, 3 K-steps. grid (12, BNP/128)
// ---------------------------------------------------------------------------
__global__ __launch_bounds__(256) void stage1_gemm(const f16* __restrict__ meta2,
                                                   const f16* __restrict__ B1t,
                                                   const float* __restrict__ bias1,
                                                   f16* __restrict__ hdn_all) {
    int c0 = blockIdx.x * 128, r0 = blockIdx.y * 128;
    __shared__ f16 As[128 * 32];
    __shared__ f16 Bs[128 * 32];
    int tid = threadIdx.x, l = tid & 63, w = tid >> 6;
    const f16* Ag = meta2 + (size_t)r0 * 96;
    const f16* Bg = B1t + (size_t)c0 * 96;
    int ch0 = w * 2, ch1 = ch0 + 1;
    int rloc = l >> 2, sl = l & 3;
    int xs = (rloc & 3) ^ ((rloc >> 2) & 1);
    int slx = (sl ^ xs) << 3;
    int rA0 = ch0 * 16 + rloc, rA1 = ch1 * 16 + rloc;
    const f16* srcA0 = Ag + (size_t)rA0 * 96 + slx;
    const f16* srcA1 = Ag + (size_t)rA1 * 96 + slx;
    const f16* srcB0 = Bg + (size_t)rA0 * 96 + slx;
    const f16* srcB1 = Bg + (size_t)rA1 * 96 + slx;
    f16* ldsA0 = As + ch0 * 512; f16* ldsA1 = As + ch1 * 512;
    f16* ldsB0 = Bs + ch0 * 512; f16* ldsB1 = Bs + ch1 * 512;

    int wr = w >> 1, wc = w & 1, lr = l & 15, hk = l >> 4;
    int xr = (lr & 3) ^ ((lr >> 2) & 1);
    const f16 *ap[4], *bp[4];
#pragma unroll
    for (int m = 0; m < 4; ++m) ap[m] = As + (wr * 64 + m * 16 + lr) * 32 + ((hk ^ xr) << 3);
#pragma unroll
    for (int n = 0; n < 4; ++n) bp[n] = Bs + (wc * 64 + n * 16 + lr) * 32 + ((hk ^ xr) << 3);

    f32x4 acc[4][4];
#pragma unroll
    for (int m = 0; m < 4; ++m)
#pragma unroll
        for (int n = 0; n < 4; ++n) acc[m][n] = (f32x4){0.f, 0.f, 0.f, 0.f};

    for (int ks = 0; ks < 3; ++ks) {
        int ko = ks * 32;
        GLOAD16(srcA0 + ko, ldsA0);
        GLOAD16(srcA1 + ko, ldsA1);
        GLOAD16(srcB0 + ko, ldsB0);
        GLOAD16(srcB1 + ko, ldsB1);
        __syncthreads();
        f16x8 a[4], b[4];
#pragma unroll
        for (int m = 0; m < 4; ++m) a[m] = *(const f16x8*)ap[m];
#pragma unroll
        for (int n = 0; n < 4; ++n) b[n] = *(const f16x8*)bp[n];
#pragma unroll
        for (int m = 0; m < 4; ++m)
#pragma unroll
            for (int n = 0; n < 4; ++n)
                acc[m][n] = __builtin_amdgcn_mfma_f32_16x16x32_f16(a[m], b[n], acc[m][n], 0, 0, 0);
        __syncthreads();
    }
    float bias[4];
#pragma unroll
    for (int n = 0; n < 4; ++n) bias[n] = bias1[c0 + wc * 64 + n * 16 + lr];
#pragma unroll
    for (int m = 0; m < 4; ++m)
#pragma unroll
        for (int reg = 0; reg < 4; ++reg) {
            int row = r0 + wr * 64 + m * 16 + hk * 4 + reg;
#pragma unroll
            for (int n = 0; n < 4; ++n) {
                int col = c0 + wc * 64 + n * 16 + lr;
                hdn_all[(size_t)row * 1536 + col] = (f16)fmaxf(acc[m][n][reg] + bias[n], 0.f);
            }
        }
}

// ---------------------------------------------------------------------------
// K5: Wh GEMM fp16 into permuted whbuf layout.
// whbuf[row][g][col'] with col' = wh_perm(h*64+k). grid (32, ceil(cr/128), 4)
// ---------------------------------------------------------------------------
__global__ __launch_bounds__(256) void gemm_wh_mfma(const f16* __restrict__ hdn_all,
                                                    const f16* __restrict__ b2t,
                                                    const float* __restrict__ wh2b,
                                                    f16* __restrict__ whbuf,
                                                    int chunk0, int chunkrows) {
    int g = blockIdx.z, col0 = blockIdx.x * 128, r0 = blockIdx.y * 128;
    __shared__ f16 As[128 * 32];
    __shared__ f16 Bt[128 * 32];
    int tid = threadIdx.x, l = tid & 63, w = tid >> 6;
    const f16* Ag = hdn_all + (size_t)(chunk0 + r0) * 1536 + 512 + g * 128;
    const f16* Bg = b2t + ((size_t)g * 4096 + col0) * 128;
    int ch0 = w * 2, ch1 = ch0 + 1;
    int rloc = l >> 2, sl = l & 3;
    int xs = (rloc & 3) ^ ((rloc >> 2) & 1);
    int slx = (sl ^ xs) << 3;
    int rA0 = ch0 * 16 + rloc, rA1 = ch1 * 16 + rloc;
    const f16* srcA0 = Ag + (size_t)rA0 * 1536 + slx;
    const f16* srcA1 = Ag + (size_t)rA1 * 1536 + slx;
    const f16* srcB0 = Bg + (size_t)rA0 * 128 + slx;
    const f16* srcB1 = Bg + (size_t)rA1 * 128 + slx;
    f16* ldsA0 = As + ch0 * 512; f16* ldsA1 = As + ch1 * 512;
    f16* ldsB0 = Bt + ch0 * 512; f16* ldsB1 = Bt + ch1 * 512;

    int wr = w >> 1, wc = w & 1, lr = l & 15, hk = l >> 4;
    int xr = (lr & 3) ^ ((lr >> 2) & 1);
    const f16 *ap[4], *bp[4];
#pragma unroll
    for (int m = 0; m < 4; ++m) ap[m] = As + (wr * 64 + m * 16 + lr) * 32 + ((hk ^ xr) << 3);
#pragma unroll
    for (int n = 0; n < 4; ++n) bp[n] = Bt + (wc * 64 + n * 16 + lr) * 32 + ((hk ^ xr) << 3);

    f32x4 acc[4][4];
#pragma unroll
    for (int m = 0; m < 4; ++m)
#pragma unroll
        for (int n = 0; n < 4; ++n) acc[m][n] = (f32x4){0.f, 0.f, 0.f, 0.f};

    for (int ks = 0; ks < 4; ++ks) {
        int ko = ks * 32;
        GLOAD16(srcA0 + ko, ldsA0);
        GLOAD16(srcA1 + ko, ldsA1);
        GLOAD16(srcB0 + ko, ldsB0);
        GLOAD16(srcB1 + ko, ldsB1);
        __syncthreads();
        f16x8 a[4], b[4];
#pragma unroll
        for (int m = 0; m < 4; ++m) a[m] = *(const f16x8*)ap[m];
#pragma unroll
        for (int n = 0; n < 4; ++n) b[n] = *(const f16x8*)bp[n];
#pragma unroll
        for (int m = 0; m < 4; ++m)
#pragma unroll
            for (int n = 0; n < 4; ++n)
                acc[m][n] = __builtin_amdgcn_mfma_f32_16x16x32_f16(a[m], b[n], acc[m][n], 0, 0, 0);
        __syncthreads();
    }
    float bias[4];
#pragma unroll
    for (int n = 0; n < 4; ++n) {
        int colp = col0 + wc * 64 + n * 16 + lr;
        bias[n] = wh2b[g * 4096 + wh_perm_inv(colp)];
    }
#pragma unroll
    for (int m = 0; m < 4; ++m)
#pragma unroll
        for (int reg = 0; reg < 4; ++reg) {
            int row = r0 + wr * 64 + m * 16 + hk * 4 + reg;
            if (row < chunkrows) {
#pragma unroll
                for (int n = 0; n < 4; ++n) {
                    int col = col0 + wc * 64 + n * 16 + lr;
                    whbuf[((size_t)row * 4 + g) * 4096 + col] = (f16)(acc[m][n][reg] + bias[n]);
                }
            }
        }
}

// ---------------------------------------------------------------------------
// K6: batched small stage-2 GEMMs: wxbb[combo][row][64], combo = a*4+g
// ---------------------------------------------------------------------------
__global__ __launch_bounds__(256) void stage2s_gemm(const f16* __restrict__ hdn_all,
                                                    const f16* __restrict__ b2s,
                                                    const float* __restrict__ bias2s,
                                                    float* __restrict__ wxbb) {
    int combo = blockIdx.y, r0 = blockIdx.x * 128;
    int a = combo >> 2, g = combo & 3;
    int aoff = (a ? 1024 : 0) + g * 128;
    __shared__ f16 As[128 * 32];
    __shared__ f16 Bs[64 * 32];
    int tid = threadIdx.x, l = tid & 63, w = tid >> 6;
    const f16* Ag = hdn_all + (size_t)r0 * 1536 + aoff;
    const f16* Bg = b2s + (size_t)combo * 8192;
    int ch0 = w * 2, ch1 = ch0 + 1;
    int rloc = l >> 2, sl = l & 3;
    int xs = (rloc & 3) ^ ((rloc >> 2) & 1);
    int slx = (sl ^ xs) << 3;
    int rA0 = ch0 * 16 + rloc, rA1 = ch1 * 16 + rloc;
    int rB  = w * 16 + rloc;
    const f16* srcA0 = Ag + (size_t)rA0 * 1536 + slx;
    const f16* srcA1 = Ag + (size_t)rA1 * 1536 + slx;
    const f16* srcB  = Bg + (size_t)rB * 128 + slx;
    f16* ldsA0 = As + ch0 * 512; f16* ldsA1 = As + ch1 * 512;
    f16* ldsB  = Bs + w * 512;

    int lr = l & 15, hk = l >> 4;
    int xr = (lr & 3) ^ ((lr >> 2) & 1);
    const f16 *ap[2], *bp[4];
#pragma unroll
    for (int m = 0; m < 2; ++m) ap[m] = As + (w * 32 + m * 16 + lr) * 32 + ((hk ^ xr) << 3);
#pragma unroll
    for (int n = 0; n < 4; ++n) bp[n] = Bs + (n * 16 + lr) * 32 + ((hk ^ xr) << 3);

    f32x4 acc[2][4];
#pragma unroll
    for (int m = 0; m < 2; ++m)
#pragma unroll
        for (int n = 0; n < 4; ++n) acc[m][n] = (f32x4){0.f, 0.f, 0.f, 0.f};

    for (int ks = 0; ks < 4; ++ks) {
        int ko = ks * 32;
        GLOAD16(srcA0 + ko, ldsA0);
        GLOAD16(srcA1 + ko, ldsA1);
        GLOAD16(srcB + ko, ldsB);
        __syncthreads();
        f16x8 av[2], bv[4];
#pragma unroll
        for (int m = 0; m < 2; ++m) av[m] = *(const f16x8*)ap[m];
#pragma unroll
        for (int n = 0; n < 4; ++n) bv[n] = *(const f16x8*)bp[n];
#pragma unroll
        for (int m = 0; m < 2; ++m)
#pragma unroll
            for (int n = 0; n < 4; ++n)
                acc[m][n] = __builtin_amdgcn_mfma_f32_16x16x32_f16(av[m], bv[n], acc[m][n], 0, 0, 0);
        __syncthreads();
    }
    float bias[4];
#pragma unroll
    for (int n = 0; n < 4; ++n) bias[n] = bias2s[combo * 64 + n * 16 + lr];
#pragma unroll
    for (int m = 0; m < 2; ++m)
#pragma unroll
        for (int reg = 0; reg < 4; ++reg) {
            int row = r0 + w * 32 + m * 16 + hk * 4 + reg;
            if (row < BN) {
#pragma unroll
                for (int n = 0; n < 4; ++n) {
                    int col = n * 16 + lr;
                    wxbb[((size_t)combo * BN + row) * 64 + col] = acc[m][n][reg] + bias[n];
                }
            }
        }
}

// ---------------------------------------------------------------------------
// K7: per-(b,n) fused LSTM (12 steps) + output head. whbuf fp16, permuted
// layout: thread (g,k) loads 8 x f16x8 contiguous (fully coalesced).
// ---------------------------------------------------------------------------
__global__ __launch_bounds__(256) void lstm_head_kernel(const f16* __restrict__ whbuf,
                                                        const float* __restrict__ wxbb,
                                                        const float* __restrict__ x,
                                                        const float* __restrict__ fc1,
                                                        const float* __restrict__ fc1b,
                                                        const float* __restrict__ fc2,
                                                        const float* __restrict__ fc2b,
                                                        float* __restrict__ out,
                                                        int chunk0) {
    int r   = blockIdx.x;
    int row = chunk0 + r;
    int b = row / NNODE, n = row - b * NNODE;
    int tid = threadIdx.x;
    int g = tid >> 6, k = tid & 63;

    // whbuf[(r*4+g)*4096 + j*512 + k*8 + e] holds Wh[h=j*8+e][k]
    const f16* wp = whbuf + ((size_t)r * 4 + g) * 4096 + k * 8;
    float whcol[64];
#pragma unroll
    for (int j = 0; j < 8; ++j) {
        f16x8 v = *(const f16x8*)(wp + j * 512);
#pragma unroll
        for (int e = 0; e < 8; ++e) whcol[j * 8 + e] = (float)v[e];
    }
    float wxv = wxbb[((size_t)g * BN + row) * HH + k];
    float bbv = wxbb[((size_t)(4 + g) * BN + row) * HH + k];

    __shared__ float xts[TT];
    __shared__ float hs[64];
    __shared__ float act[4][64];
    __shared__ float a1[32];
    if (tid < TT) xts[tid] = x[((size_t)b * TT + tid) * NNODE * XC + (size_t)n * XC];
    if (tid < 64) hs[tid] = 0.f;
    float c = 0.f;
    __syncthreads();

    for (int t = 0; t < TT; ++t) {
        float z = wxv * xts[t] + bbv;
#pragma unroll
        for (int h = 0; h < 64; h += 4) {
            float4 hv = *(const float4*)&hs[h];
            z += hv.x * whcol[h] + hv.y * whcol[h + 1] + hv.z * whcol[h + 2] + hv.w * whcol[h + 3];
        }
        float av = (g == 0) ? tanhf(z) : (1.f / (1.f + __expf(-z)));
        act[g][k] = av;
        __syncthreads();
        if (tid < 64) {
            c = act[0][tid] * act[1][tid] + c * act[2][tid];
            hs[tid] = tanhf(c) * act[3][tid];
        }
        __syncthreads();
    }
    if (tid < 32) {
        float s = fc1b[tid];
#pragma unroll
        for (int h = 0; h < 64; ++h) s += fmaxf(hs[h], 0.f) * fc1[h * 32 + tid];
        a1[tid] = fmaxf(s, 0.f);
    }
    __syncthreads();
    if (tid < OUTT) {
        float s = fc2b[tid];
#pragma unroll
        for (int j = 0; j < 32; ++j) s += a1[j] * fc2[j * OUTT + tid];
        out[((size_t)b * OUTT + tid) * NNODE + n] = s;
    }
}

// ---------------------------------------------------------------------------
extern "C" void kernel_launch(void* const* d_in, const int* in_sizes, int n_in,
                              void* d_out, int out_size, void* d_ws, size_t ws_size,
                              hipStream_t stream) {
    (void)in_sizes; (void)n_in; (void)out_size;
    const float* x    = (const float*)d_in[0];
    const float* wx1  = (const float*)d_in[1];
    const float* wx1b = (const float*)d_in[2];
    const float* wx2  = (const float*)d_in[3];
    const float* wx2b = (const float*)d_in[4];
    const float* wh1  = (const float*)d_in[5];
    const float* wh1b = (const float*)d_in[6];
    const float* wh2  = (const float*)d_in[7];
    const float* wh2b = (const float*)d_in[8];
    const float* b1   = (const float*)d_in[9];
    const float* b1b  = (const float*)d_in[10];
    const float* b2   = (const float*)d_in[11];
    const float* b2b  = (const float*)d_in[12];
    const float* fc1  = (const float*)d_in[13];
    const float* fc1b = (const float*)d_in[14];
    const float* fc2  = (const float*)d_in[15];
    const float* fc2b = (const float*)d_in[16];
    float* out = (float*)d_out;
    float* ws  = (float*)d_ws;

    float* bias1  = ws;                      // 1,536 f
    float* bias2s = bias1 + 1536;            // 512 f
    float* wxbb   = bias2s + 512;            // 5,324,800 f
    f16* meta2    = (f16*)(wxbb + 5324800);  // BNP*96
    f16* B1t      = meta2 + (size_t)BNP * 96;        // 147,456
    f16* hdn_all  = B1t + 147456;                    // BNP*1536
    f16* b2t      = hdn_all + (size_t)BNP * 1536;    // 4*4096*128
    f16* b2s      = b2t + (size_t)4 * 4096 * 128;    // 65,536
    f16* whbuf    = b2s + 65536;                     // chunk*16384

    const size_t fixedB = (size_t)(1536 + 512 + 5324800) * 4
        + ((size_t)BNP * 96 + 147456 + (size_t)BNP * 1536 + (size_t)4 * 4096 * 128 + 65536) * 2;
    size_t availB = (ws_size > fixedB) ? (ws_size - fixedB) : 0;
    long long ch = (long long)(availB / (16384 * 2));
    if (ch > 3584) ch = 3584;
    if (ch < 128)  ch = 128;
    int chunk = (int)(ch & ~127LL);

    meta2_kernel<<<(BNP * EE + 255) / 256, 256, 0, stream>>>(x, meta2);
    prep_kernel<<<840, 256, 0, stream>>>(wx1, wx1b, wx2, wx2b, wh1, wh1b,
                                         b1, b1b, b2, b2b, B1t, bias1, b2s, bias2s);
    b2t_kernel<<<dim3(64, 2, 4), 256, 0, stream>>>(wh2, b2t);
    stage1_gemm<<<dim3(12, BNP / 128), 256, 0, stream>>>(meta2, B1t, bias1, hdn_all);
    stage2s_gemm<<<dim3(BNP / 128, 8), 256, 0, stream>>>(hdn_all, b2s, bias2s, wxbb);
    for (int c0 = 0; c0 < BN; c0 += chunk) {
        int cr = BN - c0;
        if (cr > chunk) cr = chunk;
        gemm_wh_mfma<<<dim3(32, (cr + 127) / 128, 4), 256, 0, stream>>>(
            hdn_all, b2t, wh2b, whbuf, c0, cr);
        lstm_head_kernel<<<cr, 256, 0, stream>>>(whbuf, wxbb, x, fc1, fc1b,
                                                 fc2, fc2b, out, c0);
    }
}

// Round 5
// 366.726 us; speedup vs baseline: 2.9951x; 1.1066x over previous
//
#include <hip/hip_runtime.h>
#include <hip/hip_fp16.h>
#include <math.h>

#define BB   32
#define TT   12
#define NNODE 325
#define BN   (BB * NNODE)   // 10400
#define BNP  10496          // BN padded to multiple of 128
#define EE   96
#define LHH  128
#define HH   64
#define OUTT 12
#define XC   97             // 1 + E channels in x

typedef _Float16 f16;
typedef __attribute__((ext_vector_type(2))) _Float16 f16x2;
typedef __attribute__((ext_vector_type(8))) _Float16 f16x8;
typedef __attribute__((ext_vector_type(4))) float f32x4;

#define GLOAD16(g, l) __builtin_amdgcn_global_load_lds(                        \
    (const __attribute__((address_space(1))) void*)(g),                        \
    (__attribute__((address_space(3))) void*)(l), 16, 0, 0)

#if __has_builtin(__builtin_amdgcn_fdot2)
#define FDOT2(a, b, c) __builtin_amdgcn_fdot2((a), (b), (c), false)
#else
static __device__ inline float FDOT2(f16x2 a, f16x2 b, float c) {
    return c + (float)a[0] * (float)b[0] + (float)a[1] * (float)b[1];
}
#endif

static __device__ inline float fast_sig(float z) {
    return 1.f / (1.f + __expf(-z));
}
static __device__ inline float fast_tanh(float z) {
    return 2.f / (1.f + __expf(-2.f * z)) - 1.f;
}

// whbuf column permutation: original col c = h*64+k  ->  col' = (h>>3)*512 + k*8 + (h&7)
__device__ __host__ inline int wh_perm(int c) {
    return ((c >> 9) << 9) + ((c & 63) << 3) + ((c >> 6) & 7);
}
__device__ inline int wh_perm_inv(int p) {
    int j = p >> 9, k = (p >> 3) & 63, e = p & 7;
    return (j * 8 + e) * 64 + k;
}

// ---------------------------------------------------------------------------
// K1: meta2[row][e] = fp16(mean_t x[b][t][n][1+e]); pad rows (>=BN) zeroed
// ---------------------------------------------------------------------------
__global__ void meta2_kernel(const float* __restrict__ x, f16* __restrict__ meta2) {
    int idx = blockIdx.x * 256 + threadIdx.x;
    if (idx >= BNP * EE) return;
    int e = idx % EE, row = idx / EE;
    float s = 0.f;
    if (row < BN) {
        int b = row / NNODE, n = row - b * NNODE;
        const float* px = x + ((size_t)b * TT * NNODE + n) * XC + 1 + e;
#pragma unroll
        for (int t = 0; t < TT; ++t) s += px[(size_t)t * NNODE * XC];
        s *= (1.0f / 12.0f);
    }
    meta2[idx] = (f16)s;
}

// ---------------------------------------------------------------------------
// K2: prep: B1t[1536][96] fp16, bias1[1536] f32, b2s[8][64][128] fp16, bias2s
// ---------------------------------------------------------------------------
__global__ void prep_kernel(const float* __restrict__ wx1, const float* __restrict__ wx1b,
                            const float* __restrict__ wx2, const float* __restrict__ wx2b,
                            const float* __restrict__ wh1, const float* __restrict__ wh1b,
                            const float* __restrict__ b1,  const float* __restrict__ b1b,
                            const float* __restrict__ b2,  const float* __restrict__ b2b,
                            f16* __restrict__ B1t, float* __restrict__ bias1,
                            f16* __restrict__ b2s, float* __restrict__ bias2s) {
    int idx = blockIdx.x * 256 + threadIdx.x;
    if (idx < 147456) {                       // B1t[c][k] = w1[net][g][k][l]
        int c = idx / 96, k = idx - c * 96;
        int net = c >> 9, g = (c >> 7) & 3, l = c & 127;
        const float* w = (net == 0) ? wx1 : ((net == 1) ? wh1 : b1);
        B1t[idx] = (f16)w[(size_t)g * 96 * 128 + k * 128 + l];
        return;
    }
    idx -= 147456;
    if (idx < 1536) {                         // bias1[c]
        int net = idx >> 9, g = (idx >> 7) & 3, l = idx & 127;
        const float* wb = (net == 0) ? wx1b : ((net == 1) ? wh1b : b1b);
        bias1[idx] = wb[g * 128 + l];
        return;
    }
    idx -= 1536;
    if (idx < 65536) {                        // b2s[combo][cc][k] = w2[a][g][k][cc]
        int combo = idx >> 13, rem = idx & 8191, cc = rem >> 7, k = rem & 127;
        int a = combo >> 2, g = combo & 3;
        const float* w = a ? b2 : wx2;
        b2s[idx] = (f16)w[(size_t)g * 8192 + k * 64 + cc];
        return;
    }
    idx -= 65536;
    if (idx < 512) {                          // bias2s[combo][cc]
        int combo = idx >> 6, cc = idx & 63;
        int a = combo >> 2, g = combo & 3;
        bias2s[idx] = (a ? b2b : wx2b)[g * 64 + cc];
    }
}

// ---------------------------------------------------------------------------
// K3: b2t[g][wh_perm(col)][k] = fp16(wh2[g][k][col])
// ---------------------------------------------------------------------------
__global__ void b2t_kernel(const float* __restrict__ wh2, f16* __restrict__ b2t) {
    int g = blockIdx.z, l0 = blockIdx.y * 64, c0 = blockIdx.x * 64;
    __shared__ float tile[64][65];
    for (int i = threadIdx.x; i < 64 * 64; i += 256) {
        int rl = i >> 6, cc = i & 63;
        tile[rl][cc] = wh2[(size_t)(g * 128 + l0 + rl) * 4096 + c0 + cc];
    }
    __syncthreads();
    for (int i = threadIdx.x; i < 64 * 64; i += 256) {
        int cl = i >> 6, ll = i & 63;
        int colp = wh_perm(c0 + cl);
        b2t[((size_t)g * 4096 + colp) * 128 + l0 + ll] = (f16)tile[ll][cl];
    }
}

// ---------------------------------------------------------------------------
// K4: stage-1 GEMM: hdn_all[row][c] = fp16(relu(meta2 @ B1t^T + bias1))
// ---------------------------------------------------------------------------
__global__ __launch_bounds__(256) void stage1_gemm(const f16* __restrict__ meta2,
                                                   const f16* __restrict__ B1t,
                                                   const float* __restrict__ bias1,
                                                   f16* __restrict__ hdn_all) {
    int c0 = blockIdx.x * 128, r0 = blockIdx.y * 128;
    __shared__ f16 As[128 * 32];
    __shared__ f16 Bs[128 * 32];
    int tid = threadIdx.x, l = tid & 63, w = tid >> 6;
    const f16* Ag = meta2 + (size_t)r0 * 96;
    const f16* Bg = B1t + (size_t)c0 * 96;
    int ch0 = w * 2, ch1 = ch0 + 1;
    int rloc = l >> 2, sl = l & 3;
    int xs = (rloc & 3) ^ ((rloc >> 2) & 1);
    int slx = (sl ^ xs) << 3;
    int rA0 = ch0 * 16 + rloc, rA1 = ch1 * 16 + rloc;
    const f16* srcA0 = Ag + (size_t)rA0 * 96 + slx;
    const f16* srcA1 = Ag + (size_t)rA1 * 96 + slx;
    const f16* srcB0 = Bg + (size_t)rA0 * 96 + slx;
    const f16* srcB1 = Bg + (size_t)rA1 * 96 + slx;
    f16* ldsA0 = As + ch0 * 512; f16* ldsA1 = As + ch1 * 512;
    f16* ldsB0 = Bs + ch0 * 512; f16* ldsB1 = Bs + ch1 * 512;

    int wr = w >> 1, wc = w & 1, lr = l & 15, hk = l >> 4;
    int xr = (lr & 3) ^ ((lr >> 2) & 1);
    const f16 *ap[4], *bp[4];
#pragma unroll
    for (int m = 0; m < 4; ++m) ap[m] = As + (wr * 64 + m * 16 + lr) * 32 + ((hk ^ xr) << 3);
#pragma unroll
    for (int n = 0; n < 4; ++n) bp[n] = Bs + (wc * 64 + n * 16 + lr) * 32 + ((hk ^ xr) << 3);

    f32x4 acc[4][4];
#pragma unroll
    for (int m = 0; m < 4; ++m)
#pragma unroll
        for (int n = 0; n < 4; ++n) acc[m][n] = (f32x4){0.f, 0.f, 0.f, 0.f};

    for (int ks = 0; ks < 3; ++ks) {
        int ko = ks * 32;
        GLOAD16(srcA0 + ko, ldsA0);
        GLOAD16(srcA1 + ko, ldsA1);
        GLOAD16(srcB0 + ko, ldsB0);
        GLOAD16(srcB1 + ko, ldsB1);
        __syncthreads();
        f16x8 a[4], b[4];
#pragma unroll
        for (int m = 0; m < 4; ++m) a[m] = *(const f16x8*)ap[m];
#pragma unroll
        for (int n = 0; n < 4; ++n) b[n] = *(const f16x8*)bp[n];
#pragma unroll
        for (int m = 0; m < 4; ++m)
#pragma unroll
            for (int n = 0; n < 4; ++n)
                acc[m][n] = __builtin_amdgcn_mfma_f32_16x16x32_f16(a[m], b[n], acc[m][n], 0, 0, 0);
        __syncthreads();
    }
    float bias[4];
#pragma unroll
    for (int n = 0; n < 4; ++n) bias[n] = bias1[c0 + wc * 64 + n * 16 + lr];
#pragma unroll
    for (int m = 0; m < 4; ++m)
#pragma unroll
        for (int reg = 0; reg < 4; ++reg) {
            int row = r0 + wr * 64 + m * 16 + hk * 4 + reg;
#pragma unroll
            for (int n = 0; n < 4; ++n) {
                int col = c0 + wc * 64 + n * 16 + lr;
                hdn_all[(size_t)row * 1536 + col] = (f16)fmaxf(acc[m][n][reg] + bias[n], 0.f);
            }
        }
}

// ---------------------------------------------------------------------------
// K5: Wh GEMM fp16 into permuted whbuf layout.
// ---------------------------------------------------------------------------
__global__ __launch_bounds__(256) void gemm_wh_mfma(const f16* __restrict__ hdn_all,
                                                    const f16* __restrict__ b2t,
                                                    const float* __restrict__ wh2b,
                                                    f16* __restrict__ whbuf,
                                                    int chunk0, int chunkrows) {
    int g = blockIdx.z, col0 = blockIdx.x * 128, r0 = blockIdx.y * 128;
    __shared__ f16 As[128 * 32];
    __shared__ f16 Bt[128 * 32];
    int tid = threadIdx.x, l = tid & 63, w = tid >> 6;
    const f16* Ag = hdn_all + (size_t)(chunk0 + r0) * 1536 + 512 + g * 128;
    const f16* Bg = b2t + ((size_t)g * 4096 + col0) * 128;
    int ch0 = w * 2, ch1 = ch0 + 1;
    int rloc = l >> 2, sl = l & 3;
    int xs = (rloc & 3) ^ ((rloc >> 2) & 1);
    int slx = (sl ^ xs) << 3;
    int rA0 = ch0 * 16 + rloc, rA1 = ch1 * 16 + rloc;
    const f16* srcA0 = Ag + (size_t)rA0 * 1536 + slx;
    const f16* srcA1 = Ag + (size_t)rA1 * 1536 + slx;
    const f16* srcB0 = Bg + (size_t)rA0 * 128 + slx;
    const f16* srcB1 = Bg + (size_t)rA1 * 128 + slx;
    f16* ldsA0 = As + ch0 * 512; f16* ldsA1 = As + ch1 * 512;
    f16* ldsB0 = Bt + ch0 * 512; f16* ldsB1 = Bt + ch1 * 512;

    int wr = w >> 1, wc = w & 1, lr = l & 15, hk = l >> 4;
    int xr = (lr & 3) ^ ((lr >> 2) & 1);
    const f16 *ap[4], *bp[4];
#pragma unroll
    for (int m = 0; m < 4; ++m) ap[m] = As + (wr * 64 + m * 16 + lr) * 32 + ((hk ^ xr) << 3);
#pragma unroll
    for (int n = 0; n < 4; ++n) bp[n] = Bt + (wc * 64 + n * 16 + lr) * 32 + ((hk ^ xr) << 3);

    f32x4 acc[4][4];
#pragma unroll
    for (int m = 0; m < 4; ++m)
#pragma unroll
        for (int n = 0; n < 4; ++n) acc[m][n] = (f32x4){0.f, 0.f, 0.f, 0.f};

    for (int ks = 0; ks < 4; ++ks) {
        int ko = ks * 32;
        GLOAD16(srcA0 + ko, ldsA0);
        GLOAD16(srcA1 + ko, ldsA1);
        GLOAD16(srcB0 + ko, ldsB0);
        GLOAD16(srcB1 + ko, ldsB1);
        __syncthreads();
        f16x8 a[4], b[4];
#pragma unroll
        for (int m = 0; m < 4; ++m) a[m] = *(const f16x8*)ap[m];
#pragma unroll
        for (int n = 0; n < 4; ++n) b[n] = *(const f16x8*)bp[n];
#pragma unroll
        for (int m = 0; m < 4; ++m)
#pragma unroll
            for (int n = 0; n < 4; ++n)
                acc[m][n] = __builtin_amdgcn_mfma_f32_16x16x32_f16(a[m], b[n], acc[m][n], 0, 0, 0);
        __syncthreads();
    }
    float bias[4];
#pragma unroll
    for (int n = 0; n < 4; ++n) {
        int colp = col0 + wc * 64 + n * 16 + lr;
        bias[n] = wh2b[g * 4096 + wh_perm_inv(colp)];
    }
#pragma unroll
    for (int m = 0; m < 4; ++m)
#pragma unroll
        for (int reg = 0; reg < 4; ++reg) {
            int row = r0 + wr * 64 + m * 16 + hk * 4 + reg;
            if (row < chunkrows) {
#pragma unroll
                for (int n = 0; n < 4; ++n) {
                    int col = col0 + wc * 64 + n * 16 + lr;
                    whbuf[((size_t)row * 4 + g) * 4096 + col] = (f16)(acc[m][n][reg] + bias[n]);
                }
            }
        }
}

// ---------------------------------------------------------------------------
// K6: batched small stage-2 GEMMs: wxbb[combo][row][64], combo = a*4+g
// ---------------------------------------------------------------------------
__global__ __launch_bounds__(256) void stage2s_gemm(const f16* __restrict__ hdn_all,
                                                    const f16* __restrict__ b2s,
                                                    const float* __restrict__ bias2s,
                                                    float* __restrict__ wxbb) {
    int combo = blockIdx.y, r0 = blockIdx.x * 128;
    int a = combo >> 2, g = combo & 3;
    int aoff = (a ? 1024 : 0) + g * 128;
    __shared__ f16 As[128 * 32];
    __shared__ f16 Bs[64 * 32];
    int tid = threadIdx.x, l = tid & 63, w = tid >> 6;
    const f16* Ag = hdn_all + (size_t)r0 * 1536 + aoff;
    const f16* Bg = b2s + (size_t)combo * 8192;
    int ch0 = w * 2, ch1 = ch0 + 1;
    int rloc = l >> 2, sl = l & 3;
    int xs = (rloc & 3) ^ ((rloc >> 2) & 1);
    int slx = (sl ^ xs) << 3;
    int rA0 = ch0 * 16 + rloc, rA1 = ch1 * 16 + rloc;
    int rB  = w * 16 + rloc;
    const f16* srcA0 = Ag + (size_t)rA0 * 1536 + slx;
    const f16* srcA1 = Ag + (size_t)rA1 * 1536 + slx;
    const f16* srcB  = Bg + (size_t)rB * 128 + slx;
    f16* ldsA0 = As + ch0 * 512; f16* ldsA1 = As + ch1 * 512;
    f16* ldsB  = Bs + w * 512;

    int lr = l & 15, hk = l >> 4;
    int xr = (lr & 3) ^ ((lr >> 2) & 1);
    const f16 *ap[2], *bp[4];
#pragma unroll
    for (int m = 0; m < 2; ++m) ap[m] = As + (w * 32 + m * 16 + lr) * 32 + ((hk ^ xr) << 3);
#pragma unroll
    for (int n = 0; n < 4; ++n) bp[n] = Bs + (n * 16 + lr) * 32 + ((hk ^ xr) << 3);

    f32x4 acc[2][4];
#pragma unroll
    for (int m = 0; m < 2; ++m)
#pragma unroll
        for (int n = 0; n < 4; ++n) acc[m][n] = (f32x4){0.f, 0.f, 0.f, 0.f};

    for (int ks = 0; ks < 4; ++ks) {
        int ko = ks * 32;
        GLOAD16(srcA0 + ko, ldsA0);
        GLOAD16(srcA1 + ko, ldsA1);
        GLOAD16(srcB + ko, ldsB);
        __syncthreads();
        f16x8 av[2], bv[4];
#pragma unroll
        for (int m = 0; m < 2; ++m) av[m] = *(const f16x8*)ap[m];
#pragma unroll
        for (int n = 0; n < 4; ++n) bv[n] = *(const f16x8*)bp[n];
#pragma unroll
        for (int m = 0; m < 2; ++m)
#pragma unroll
            for (int n = 0; n < 4; ++n)
                acc[m][n] = __builtin_amdgcn_mfma_f32_16x16x32_f16(av[m], bv[n], acc[m][n], 0, 0, 0);
        __syncthreads();
    }
    float bias[4];
#pragma unroll
    for (int n = 0; n < 4; ++n) bias[n] = bias2s[combo * 64 + n * 16 + lr];
#pragma unroll
    for (int m = 0; m < 2; ++m)
#pragma unroll
        for (int reg = 0; reg < 4; ++reg) {
            int row = r0 + w * 32 + m * 16 + hk * 4 + reg;
            if (row < BN) {
#pragma unroll
                for (int n = 0; n < 4; ++n) {
                    int col = n * 16 + lr;
                    wxbb[((size_t)combo * BN + row) * 64 + col] = acc[m][n][reg] + bias[n];
                }
            }
        }
}

// ---------------------------------------------------------------------------
// K7: wave-per-row LSTM + head. Zero barriers. Lane k holds all 4 gates'
// Wh columns in registers (f16, 128 VGPRs); h kept in per-wave LDS as f16;
// gate dots via v_dot2_f32_f16; gates/c/h update fully lane-local.
// grid = ceil(cr/4), block 256 (4 independent waves).
// ---------------------------------------------------------------------------
__global__ __launch_bounds__(256) void lstm_head_kernel(const f16* __restrict__ whbuf,
                                                        const float* __restrict__ wxbb,
                                                        const float* __restrict__ x,
                                                        const float* __restrict__ fc1,
                                                        const float* __restrict__ fc1b,
                                                        const float* __restrict__ fc2,
                                                        const float* __restrict__ fc2b,
                                                        float* __restrict__ out,
                                                        int chunk0, int chunkrows) {
    __shared__ __align__(16) f16 hs[4][64];
    __shared__ float xts[4][TT];
    __shared__ float a1s[4][32];
    int w = threadIdx.x >> 6, lane = threadIdx.x & 63;
    int r = blockIdx.x * 4 + w;
    if (r >= chunkrows) return;
    int row = chunk0 + r;
    int b = row / NNODE, n = row - b * NNODE;
    int k = lane;

    // Wh columns: whbuf[(r*4+g)*4096 + jj*512 + k*8 + e] = Wh[g][h=jj*8+e][k]
    const f16* wp = whbuf + ((size_t)r * 4) * 4096 + k * 8;
    f16x8 wh[4][8];
#pragma unroll
    for (int g = 0; g < 4; ++g)
#pragma unroll
        for (int jj = 0; jj < 8; ++jj)
            wh[g][jj] = *(const f16x8*)(wp + (size_t)g * 4096 + jj * 512);

    float wxv[4], bbv[4];
#pragma unroll
    for (int g = 0; g < 4; ++g) {
        wxv[g] = wxbb[((size_t)g * BN + row) * HH + k];
        bbv[g] = wxbb[((size_t)(4 + g) * BN + row) * HH + k];
    }
    if (lane < TT) xts[w][lane] = x[((size_t)b * TT + lane) * NNODE * XC + (size_t)n * XC];
    hs[w][k] = (f16)0.f;
    // intra-wave LDS ops are in-order; no barrier needed (waves independent)

    float c = 0.f;
    for (int t = 0; t < TT; ++t) {
        float xt = xts[w][t];
        float z0 = wxv[0] * xt + bbv[0];
        float z1 = wxv[1] * xt + bbv[1];
        float z2 = wxv[2] * xt + bbv[2];
        float z3 = wxv[3] * xt + bbv[3];
#pragma unroll
        for (int jj = 0; jj < 8; ++jj) {
            f16x8 hv = ((const f16x8*)hs[w])[jj];      // broadcast read
#pragma unroll
            for (int p = 0; p < 4; ++p) {
                f16x2 hp = {hv[2 * p], hv[2 * p + 1]};
                f16x2 w0 = {wh[0][jj][2 * p], wh[0][jj][2 * p + 1]};
                f16x2 w1 = {wh[1][jj][2 * p], wh[1][jj][2 * p + 1]};
                f16x2 w2 = {wh[2][jj][2 * p], wh[2][jj][2 * p + 1]};
                f16x2 w3 = {wh[3][jj][2 * p], wh[3][jj][2 * p + 1]};
                z0 = FDOT2(w0, hp, z0);
                z1 = FDOT2(w1, hp, z1);
                z2 = FDOT2(w2, hp, z2);
                z3 = FDOT2(w3, hp, z3);
            }
        }
        float gg = fast_tanh(z0);
        float ii = fast_sig(z1);
        float ff = fast_sig(z2);
        float oo = fast_sig(z3);
        c = gg * ii + c * ff;
        hs[w][k] = (f16)(fast_tanh(c) * oo);
    }
    // head (in-wave): a1 = relu(relu(h) @ fc1 + b1); out = a1 @ fc2 + b2
    if (lane < 32) {
        float s = fc1b[lane];
#pragma unroll
        for (int h = 0; h < 64; ++h)
            s += fmaxf((float)hs[w][h], 0.f) * fc1[h * 32 + lane];
        a1s[w][lane] = fmaxf(s, 0.f);
    }
    if (lane < OUTT) {
        float s = fc2b[lane];
#pragma unroll
        for (int j = 0; j < 32; ++j) s += a1s[w][j] * fc2[j * OUTT + lane];
        out[((size_t)b * OUTT + lane) * NNODE + n] = s;
    }
}

// ---------------------------------------------------------------------------
extern "C" void kernel_launch(void* const* d_in, const int* in_sizes, int n_in,
                              void* d_out, int out_size, void* d_ws, size_t ws_size,
                              hipStream_t stream) {
    (void)in_sizes; (void)n_in; (void)out_size;
    const float* x    = (const float*)d_in[0];
    const float* wx1  = (const float*)d_in[1];
    const float* wx1b = (const float*)d_in[2];
    const float* wx2  = (const float*)d_in[3];
    const float* wx2b = (const float*)d_in[4];
    const float* wh1  = (const float*)d_in[5];
    const float* wh1b = (const float*)d_in[6];
    const float* wh2  = (const float*)d_in[7];
    const float* wh2b = (const float*)d_in[8];
    const float* b1   = (const float*)d_in[9];
    const float* b1b  = (const float*)d_in[10];
    const float* b2   = (const float*)d_in[11];
    const float* b2b  = (const float*)d_in[12];
    const float* fc1  = (const float*)d_in[13];
    const float* fc1b = (const float*)d_in[14];
    const float* fc2  = (const float*)d_in[15];
    const float* fc2b = (const float*)d_in[16];
    float* out = (float*)d_out;
    float* ws  = (float*)d_ws;

    float* bias1  = ws;                      // 1,536 f
    float* bias2s = bias1 + 1536;            // 512 f
    float* wxbb   = bias2s + 512;            // 5,324,800 f
    f16* meta2    = (f16*)(wxbb + 5324800);  // BNP*96
    f16* B1t      = meta2 + (size_t)BNP * 96;        // 147,456
    f16* hdn_all  = B1t + 147456;                    // BNP*1536
    f16* b2t      = hdn_all + (size_t)BNP * 1536;    // 4*4096*128
    f16* b2s      = b2t + (size_t)4 * 4096 * 128;    // 65,536
    f16* whbuf    = b2s + 65536;                     // chunk*16384

    const size_t fixedB = (size_t)(1536 + 512 + 5324800) * 4
        + ((size_t)BNP * 96 + 147456 + (size_t)BNP * 1536 + (size_t)4 * 4096 * 128 + 65536) * 2;
    size_t availB = (ws_size > fixedB) ? (ws_size - fixedB) : 0;
    long long ch = (long long)(availB / (16384 * 2));
    if (ch > 3584) ch = 3584;
    if (ch < 128)  ch = 128;
    int chunk = (int)(ch & ~127LL);

    meta2_kernel<<<(BNP * EE + 255) / 256, 256, 0, stream>>>(x, meta2);
    prep_kernel<<<840, 256, 0, stream>>>(wx1, wx1b, wx2, wx2b, wh1, wh1b,
                                         b1, b1b, b2, b2b, B1t, bias1, b2s, bias2s);
    b2t_kernel<<<dim3(64, 2, 4), 256, 0, stream>>>(wh2, b2t);
    stage1_gemm<<<dim3(12, BNP / 128), 256, 0, stream>>>(meta2, B1t, bias1, hdn_all);
    stage2s_gemm<<<dim3(BNP / 128, 8), 256, 0, stream>>>(hdn_all, b2s, bias2s, wxbb);
    for (int c0 = 0; c0 < BN; c0 += chunk) {
        int cr = BN - c0;
        if (cr > chunk) cr = chunk;
        gemm_wh_mfma<<<dim3(32, (cr + 127) / 128, 4), 256, 0, stream>>>(
            hdn_all, b2t, wh2b, whbuf, c0, cr);
        lstm_head_kernel<<<(cr + 3) / 4, 256, 0, stream>>>(whbuf, wxbb, x, fc1, fc1b,
                                                           fc2, fc2b, out, c0, cr);
    }
}

// Round 6
// 335.788 us; speedup vs baseline: 3.2711x; 1.0921x over previous
//
#include <hip/hip_runtime.h>
#include <hip/hip_fp16.h>
#include <math.h>

#define BB   32
#define TT   12
#define NNODE 325
#define BN   (BB * NNODE)   // 10400
#define BNP  10496          // BN padded to multiple of 128
#define EE   96
#define LHH  128
#define HH   64
#define OUTT 12
#define XC   97             // 1 + E channels in x

typedef _Float16 f16;
typedef __attribute__((ext_vector_type(2))) _Float16 f16x2;
typedef __attribute__((ext_vector_type(8))) _Float16 f16x8;
typedef __attribute__((ext_vector_type(4))) float f32x4;

#define GLOAD16(g, l) __builtin_amdgcn_global_load_lds(                        \
    (const __attribute__((address_space(1))) void*)(g),                        \
    (__attribute__((address_space(3))) void*)(l), 16, 0, 0)

#if __has_builtin(__builtin_amdgcn_fdot2)
#define FDOT2(a, b, c) __builtin_amdgcn_fdot2((a), (b), (c), false)
#else
static __device__ inline float FDOT2(f16x2 a, f16x2 b, float c) {
    return c + (float)a[0] * (float)b[0] + (float)a[1] * (float)b[1];
}
#endif

static __device__ inline float fast_sig(float z) {
    return 1.f / (1.f + __expf(-z));
}
static __device__ inline float fast_tanh(float z) {
    return 2.f / (1.f + __expf(-2.f * z)) - 1.f;
}

// whbuf column permutation: original col c = h*64+k  ->  col' = (h>>3)*512 + k*8 + (h&7)
__device__ __host__ inline int wh_perm(int c) {
    return ((c >> 9) << 9) + ((c & 63) << 3) + ((c >> 6) & 7);
}
__device__ inline int wh_perm_inv(int p) {
    int j = p >> 9, k = (p >> 3) & 63, e = p & 7;
    return (j * 8 + e) * 64 + k;
}

// ---------------------------------------------------------------------------
// K1: meta2[row][e(128 padded)] = fp16(mean_t x[b][t][n][1+e]); pads zeroed
// ---------------------------------------------------------------------------
__global__ void meta2_kernel(const float* __restrict__ x, f16* __restrict__ meta2) {
    int idx = blockIdx.x * 256 + threadIdx.x;
    if (idx >= BNP * 128) return;
    int e = idx & 127, row = idx >> 7;
    float s = 0.f;
    if (row < BN && e < EE) {
        int b = row / NNODE, n = row - b * NNODE;
        const float* px = x + ((size_t)b * TT * NNODE + n) * XC + 1 + e;
#pragma unroll
        for (int t = 0; t < TT; ++t) s += px[(size_t)t * NNODE * XC];
        s *= (1.0f / 12.0f);
    }
    meta2[idx] = (f16)s;
}

// ---------------------------------------------------------------------------
// K2: merged prep (B1t[1536][128] K-padded, bias1, b2s, bias2s) + b2t build
// grid 1032 + 512 blocks
// ---------------------------------------------------------------------------
__global__ void prep_b2t_kernel(const float* __restrict__ wx1, const float* __restrict__ wx1b,
                                const float* __restrict__ wx2, const float* __restrict__ wx2b,
                                const float* __restrict__ wh1, const float* __restrict__ wh1b,
                                const float* __restrict__ b1,  const float* __restrict__ b1b,
                                const float* __restrict__ b2,  const float* __restrict__ b2b,
                                const float* __restrict__ wh2,
                                f16* __restrict__ B1t, float* __restrict__ bias1,
                                f16* __restrict__ b2s, float* __restrict__ bias2s,
                                f16* __restrict__ b2t) {
    __shared__ float tile[64][65];
    int bx = blockIdx.x;
    if (bx < 1032) {
        int idx = bx * 256 + threadIdx.x;
        if (idx < 196608) {                   // B1t[c][k] (k<96 real, else 0)
            int c = idx >> 7, k = idx & 127;
            int net = c >> 9, g = (c >> 7) & 3, l = c & 127;
            const float* w = (net == 0) ? wx1 : ((net == 1) ? wh1 : b1);
            B1t[idx] = (k < 96) ? (f16)w[(size_t)g * 12288 + k * 128 + l] : (f16)0.f;
            return;
        }
        idx -= 196608;
        if (idx < 1536) {
            int net = idx >> 9, g = (idx >> 7) & 3, l = idx & 127;
            const float* wb = (net == 0) ? wx1b : ((net == 1) ? wh1b : b1b);
            bias1[idx] = wb[g * 128 + l];
            return;
        }
        idx -= 1536;
        if (idx < 65536) {                    // b2s[combo][cc][k]
            int combo = idx >> 13, rem = idx & 8191, cc = rem >> 7, k = rem & 127;
            int a = combo >> 2, g = combo & 3;
            const float* w = a ? b2 : wx2;
            b2s[idx] = (f16)w[(size_t)g * 8192 + k * 64 + cc];
            return;
        }
        idx -= 65536;
        if (idx < 512) {
            int combo = idx >> 6, cc = idx & 63;
            int a = combo >> 2, g = combo & 3;
            bias2s[idx] = (a ? b2b : wx2b)[g * 64 + cc];
        }
        return;
    }
    // b2t part: b2t[g][wh_perm(col)][k] = fp16(wh2[g][k][col])
    int bid = bx - 1032;
    int g = bid >> 7, l0 = ((bid >> 6) & 1) * 64, c0 = (bid & 63) * 64;
    for (int i = threadIdx.x; i < 64 * 64; i += 256) {
        int rl = i >> 6, cc = i & 63;
        tile[rl][cc] = wh2[(size_t)(g * 128 + l0 + rl) * 4096 + c0 + cc];
    }
    __syncthreads();
    for (int i = threadIdx.x; i < 64 * 64; i += 256) {
        int cl = i >> 6, ll = i & 63;
        int colp = wh_perm(c0 + cl);
        b2t[((size_t)g * 4096 + colp) * 128 + l0 + ll] = (f16)tile[ll][cl];
    }
}

// ---------------------------------------------------------------------------
// K3: single-stage stage-1 GEMM (K=128 padded): hdn_all = relu(meta2 @ B1t^T + b)
// 128x128 tile; whole K staged once; 1 drain; 64 MFMA; LDS-bounce epilogue.
// grid (12, BNP/128)
// ---------------------------------------------------------------------------
__global__ __launch_bounds__(256) void stage1_gemm(const f16* __restrict__ meta2,
                                                   const f16* __restrict__ B1t,
                                                   const float* __restrict__ bias1,
                                                   f16* __restrict__ hdn_all) {
    __shared__ f16 smem[32768];              // As 16K f16 | Bs 16K f16 ; outT reuse
    f16* As = smem;
    f16* Bs = smem + 16384;
    int c0 = blockIdx.x * 128, r0 = blockIdx.y * 128;
    int tid = threadIdx.x, w = tid >> 6;
    const f16* Ag = meta2 + (size_t)r0 * 128;
    const f16* Bg = B1t + (size_t)c0 * 128;
    int srow = tid >> 4;
    int scol = ((tid & 15) ^ (srow & 15)) << 3;
#pragma unroll
    for (int j = 0; j < 8; ++j)
        GLOAD16(Ag + (size_t)(j * 16 + srow) * 128 + scol, As + j * 2048 + w * 512);
#pragma unroll
    for (int j = 0; j < 8; ++j)
        GLOAD16(Bg + (size_t)(j * 16 + srow) * 128 + scol, Bs + j * 2048 + w * 512);

    int l = tid & 63, wr = w >> 1, wc = w & 1, lr = l & 15, hk = l >> 4;
    const f16 *ar[4], *br[4];
#pragma unroll
    for (int m = 0; m < 4; ++m) ar[m] = As + (wr * 64 + m * 16 + lr) * 128;
#pragma unroll
    for (int n = 0; n < 4; ++n) br[n] = Bs + (wc * 64 + n * 16 + lr) * 128;

    f32x4 acc[4][4];
#pragma unroll
    for (int m = 0; m < 4; ++m)
#pragma unroll
        for (int n = 0; n < 4; ++n) acc[m][n] = (f32x4){0.f, 0.f, 0.f, 0.f};

    __syncthreads();                          // drains staging (vmcnt 0)
#pragma unroll
    for (int kk = 0; kk < 4; ++kk) {
        int so = (((kk * 4 + hk) ^ lr) << 3);
        f16x8 a[4], b[4];
#pragma unroll
        for (int m = 0; m < 4; ++m) a[m] = *(const f16x8*)(ar[m] + so);
#pragma unroll
        for (int n = 0; n < 4; ++n) b[n] = *(const f16x8*)(br[n] + so);
#pragma unroll
        for (int m = 0; m < 4; ++m)
#pragma unroll
            for (int n = 0; n < 4; ++n)
                acc[m][n] = __builtin_amdgcn_mfma_f32_16x16x32_f16(a[m], b[n], acc[m][n], 0, 0, 0);
    }
    float bias[4];
#pragma unroll
    for (int n = 0; n < 4; ++n) bias[n] = bias1[c0 + wc * 64 + n * 16 + lr];
    __syncthreads();                          // frags consumed; reuse smem as outT
    f16* outT = smem;                         // [128][136]
#pragma unroll
    for (int m = 0; m < 4; ++m)
#pragma unroll
        for (int reg = 0; reg < 4; ++reg) {
            int rowL = wr * 64 + m * 16 + hk * 4 + reg;
#pragma unroll
            for (int n = 0; n < 4; ++n)
                outT[rowL * 136 + wc * 64 + n * 16 + lr] =
                    (f16)fmaxf(acc[m][n][reg] + bias[n], 0.f);
        }
    __syncthreads();
#pragma unroll
    for (int pass = 0; pass < 8; ++pass) {
        int rowL = pass * 16 + (tid >> 4);
        int sc = (tid & 15) << 3;
        f16x8 v = *(const f16x8*)(outT + rowL * 136 + sc);
        *(f16x8*)(hdn_all + (size_t)(r0 + rowL) * 1536 + c0 + sc) = v;
    }
}

// ---------------------------------------------------------------------------
// K4: single-stage Wh GEMM (K=128) into permuted whbuf. grid (32, ceil/128, 4)
// ---------------------------------------------------------------------------
__global__ __launch_bounds__(256) void gemm_wh_mfma(const f16* __restrict__ hdn_all,
                                                    const f16* __restrict__ b2t,
                                                    const float* __restrict__ wh2b,
                                                    f16* __restrict__ whbuf,
                                                    int chunk0, int chunkrows) {
    __shared__ f16 smem[32768];
    f16* As = smem;
    f16* Bs = smem + 16384;
    int g = blockIdx.z, col0 = blockIdx.x * 128, r0 = blockIdx.y * 128;
    int tid = threadIdx.x, w = tid >> 6;
    const f16* Ag = hdn_all + (size_t)(chunk0 + r0) * 1536 + 512 + g * 128;
    const f16* Bg = b2t + ((size_t)g * 4096 + col0) * 128;
    int srow = tid >> 4;
    int scol = ((tid & 15) ^ (srow & 15)) << 3;
#pragma unroll
    for (int j = 0; j < 8; ++j)
        GLOAD16(Ag + (size_t)(j * 16 + srow) * 1536 + scol, As + j * 2048 + w * 512);
#pragma unroll
    for (int j = 0; j < 8; ++j)
        GLOAD16(Bg + (size_t)(j * 16 + srow) * 128 + scol, Bs + j * 2048 + w * 512);

    int l = tid & 63, wr = w >> 1, wc = w & 1, lr = l & 15, hk = l >> 4;
    const f16 *ar[4], *br[4];
#pragma unroll
    for (int m = 0; m < 4; ++m) ar[m] = As + (wr * 64 + m * 16 + lr) * 128;
#pragma unroll
    for (int n = 0; n < 4; ++n) br[n] = Bs + (wc * 64 + n * 16 + lr) * 128;

    f32x4 acc[4][4];
#pragma unroll
    for (int m = 0; m < 4; ++m)
#pragma unroll
        for (int n = 0; n < 4; ++n) acc[m][n] = (f32x4){0.f, 0.f, 0.f, 0.f};

    __syncthreads();
#pragma unroll
    for (int kk = 0; kk < 4; ++kk) {
        int so = (((kk * 4 + hk) ^ lr) << 3);
        f16x8 a[4], b[4];
#pragma unroll
        for (int m = 0; m < 4; ++m) a[m] = *(const f16x8*)(ar[m] + so);
#pragma unroll
        for (int n = 0; n < 4; ++n) b[n] = *(const f16x8*)(br[n] + so);
#pragma unroll
        for (int m = 0; m < 4; ++m)
#pragma unroll
            for (int n = 0; n < 4; ++n)
                acc[m][n] = __builtin_amdgcn_mfma_f32_16x16x32_f16(a[m], b[n], acc[m][n], 0, 0, 0);
    }
    float bias[4];
#pragma unroll
    for (int n = 0; n < 4; ++n) {
        int colp = col0 + wc * 64 + n * 16 + lr;
        bias[n] = wh2b[g * 4096 + wh_perm_inv(colp)];
    }
    __syncthreads();
    f16* outT = smem;                         // [128][136]
#pragma unroll
    for (int m = 0; m < 4; ++m)
#pragma unroll
        for (int reg = 0; reg < 4; ++reg) {
            int rowL = wr * 64 + m * 16 + hk * 4 + reg;
#pragma unroll
            for (int n = 0; n < 4; ++n)
                outT[rowL * 136 + wc * 64 + n * 16 + lr] = (f16)(acc[m][n][reg] + bias[n]);
        }
    __syncthreads();
#pragma unroll
    for (int pass = 0; pass < 8; ++pass) {
        int rowL = pass * 16 + (tid >> 4);
        int row = r0 + rowL;
        if (row < chunkrows) {
            int sc = (tid & 15) << 3;
            f16x8 v = *(const f16x8*)(outT + rowL * 136 + sc);
            *(f16x8*)(whbuf + ((size_t)row * 4 + g) * 4096 + col0 + sc) = v;
        }
    }
}

// ---------------------------------------------------------------------------
// K5: single-stage batched stage-2 GEMMs: wxbb[combo][row][64]. grid (82, 8)
// ---------------------------------------------------------------------------
__global__ __launch_bounds__(256) void stage2s_gemm(const f16* __restrict__ hdn_all,
                                                    const f16* __restrict__ b2s,
                                                    const float* __restrict__ bias2s,
                                                    float* __restrict__ wxbb) {
    __shared__ f16 smem[24576];               // As 16K | Bs 8K
    f16* As = smem;
    f16* Bs = smem + 16384;
    int combo = blockIdx.y, r0 = blockIdx.x * 128;
    int a = combo >> 2, g = combo & 3;
    int aoff = (a ? 1024 : 0) + g * 128;
    int tid = threadIdx.x, w = tid >> 6;
    const f16* Ag = hdn_all + (size_t)r0 * 1536 + aoff;
    const f16* Bg = b2s + (size_t)combo * 8192;
    int srow = tid >> 4;
    int scol = ((tid & 15) ^ (srow & 15)) << 3;
#pragma unroll
    for (int j = 0; j < 8; ++j)
        GLOAD16(Ag + (size_t)(j * 16 + srow) * 1536 + scol, As + j * 2048 + w * 512);
#pragma unroll
    for (int j = 0; j < 4; ++j)
        GLOAD16(Bg + (size_t)(j * 16 + srow) * 128 + scol, Bs + j * 2048 + w * 512);

    int l = tid & 63, lr = l & 15, hk = l >> 4;
    const f16 *ar[2], *br[4];
#pragma unroll
    for (int m = 0; m < 2; ++m) ar[m] = As + (w * 32 + m * 16 + lr) * 128;
#pragma unroll
    for (int n = 0; n < 4; ++n) br[n] = Bs + (n * 16 + lr) * 128;

    f32x4 acc[2][4];
#pragma unroll
    for (int m = 0; m < 2; ++m)
#pragma unroll
        for (int n = 0; n < 4; ++n) acc[m][n] = (f32x4){0.f, 0.f, 0.f, 0.f};

    __syncthreads();
#pragma unroll
    for (int kk = 0; kk < 4; ++kk) {
        int so = (((kk * 4 + hk) ^ lr) << 3);
        f16x8 av[2], bv[4];
#pragma unroll
        for (int m = 0; m < 2; ++m) av[m] = *(const f16x8*)(ar[m] + so);
#pragma unroll
        for (int n = 0; n < 4; ++n) bv[n] = *(const f16x8*)(br[n] + so);
#pragma unroll
        for (int m = 0; m < 2; ++m)
#pragma unroll
            for (int n = 0; n < 4; ++n)
                acc[m][n] = __builtin_amdgcn_mfma_f32_16x16x32_f16(av[m], bv[n], acc[m][n], 0, 0, 0);
    }
    float bias[4];
#pragma unroll
    for (int n = 0; n < 4; ++n) bias[n] = bias2s[combo * 64 + n * 16 + lr];
#pragma unroll
    for (int m = 0; m < 2; ++m)
#pragma unroll
        for (int reg = 0; reg < 4; ++reg) {
            int row = r0 + w * 32 + m * 16 + hk * 4 + reg;
            if (row < BN) {
#pragma unroll
                for (int n = 0; n < 4; ++n) {
                    int col = n * 16 + lr;
                    wxbb[((size_t)combo * BN + row) * 64 + col] = acc[m][n][reg] + bias[n];
                }
            }
        }
}

// ---------------------------------------------------------------------------
// K6: wave-per-row LSTM + head (zero barriers, fdot2, fast activations)
// ---------------------------------------------------------------------------
__global__ __launch_bounds__(256) void lstm_head_kernel(const f16* __restrict__ whbuf,
                                                        const float* __restrict__ wxbb,
                                                        const float* __restrict__ x,
                                                        const float* __restrict__ fc1,
                                                        const float* __restrict__ fc1b,
                                                        const float* __restrict__ fc2,
                                                        const float* __restrict__ fc2b,
                                                        float* __restrict__ out,
                                                        int chunk0, int chunkrows) {
    __shared__ __align__(16) f16 hs[4][64];
    __shared__ float xts[4][TT];
    __shared__ float a1s[4][32];
    int w = threadIdx.x >> 6, lane = threadIdx.x & 63;
    int r = blockIdx.x * 4 + w;
    if (r >= chunkrows) return;
    int row = chunk0 + r;
    int b = row / NNODE, n = row - b * NNODE;
    int k = lane;

    const f16* wp = whbuf + ((size_t)r * 4) * 4096 + k * 8;
    f16x8 wh[4][8];
#pragma unroll
    for (int g = 0; g < 4; ++g)
#pragma unroll
        for (int jj = 0; jj < 8; ++jj)
            wh[g][jj] = *(const f16x8*)(wp + (size_t)g * 4096 + jj * 512);

    float wxv[4], bbv[4];
#pragma unroll
    for (int g = 0; g < 4; ++g) {
        wxv[g] = wxbb[((size_t)g * BN + row) * HH + k];
        bbv[g] = wxbb[((size_t)(4 + g) * BN + row) * HH + k];
    }
    if (lane < TT) xts[w][lane] = x[((size_t)b * TT + lane) * NNODE * XC + (size_t)n * XC];
    hs[w][k] = (f16)0.f;

    float c = 0.f;
    for (int t = 0; t < TT; ++t) {
        float xt = xts[w][t];
        float z0 = wxv[0] * xt + bbv[0];
        float z1 = wxv[1] * xt + bbv[1];
        float z2 = wxv[2] * xt + bbv[2];
        float z3 = wxv[3] * xt + bbv[3];
#pragma unroll
        for (int jj = 0; jj < 8; ++jj) {
            f16x8 hv = ((const f16x8*)hs[w])[jj];
#pragma unroll
            for (int p = 0; p < 4; ++p) {
                f16x2 hp = {hv[2 * p], hv[2 * p + 1]};
                f16x2 w0 = {wh[0][jj][2 * p], wh[0][jj][2 * p + 1]};
                f16x2 w1 = {wh[1][jj][2 * p], wh[1][jj][2 * p + 1]};
                f16x2 w2 = {wh[2][jj][2 * p], wh[2][jj][2 * p + 1]};
                f16x2 w3 = {wh[3][jj][2 * p], wh[3][jj][2 * p + 1]};
                z0 = FDOT2(w0, hp, z0);
                z1 = FDOT2(w1, hp, z1);
                z2 = FDOT2(w2, hp, z2);
                z3 = FDOT2(w3, hp, z3);
            }
        }
        float gg = fast_tanh(z0);
        float ii = fast_sig(z1);
        float ff = fast_sig(z2);
        float oo = fast_sig(z3);
        c = gg * ii + c * ff;
        hs[w][k] = (f16)(fast_tanh(c) * oo);
    }
    if (lane < 32) {
        float s = fc1b[lane];
#pragma unroll
        for (int h = 0; h < 64; ++h)
            s += fmaxf((float)hs[w][h], 0.f) * fc1[h * 32 + lane];
        a1s[w][lane] = fmaxf(s, 0.f);
    }
    if (lane < OUTT) {
        float s = fc2b[lane];
#pragma unroll
        for (int j = 0; j < 32; ++j) s += a1s[w][j] * fc2[j * OUTT + lane];
        out[((size_t)b * OUTT + lane) * NNODE + n] = s;
    }
}

// ---------------------------------------------------------------------------
extern "C" void kernel_launch(void* const* d_in, const int* in_sizes, int n_in,
                              void* d_out, int out_size, void* d_ws, size_t ws_size,
                              hipStream_t stream) {
    (void)in_sizes; (void)n_in; (void)out_size;
    const float* x    = (const float*)d_in[0];
    const float* wx1  = (const float*)d_in[1];
    const float* wx1b = (const float*)d_in[2];
    const float* wx2  = (const float*)d_in[3];
    const float* wx2b = (const float*)d_in[4];
    const float* wh1  = (const float*)d_in[5];
    const float* wh1b = (const float*)d_in[6];
    const float* wh2  = (const float*)d_in[7];
    const float* wh2b = (const float*)d_in[8];
    const float* b1   = (const float*)d_in[9];
    const float* b1b  = (const float*)d_in[10];
    const float* b2   = (const float*)d_in[11];
    const float* b2b  = (const float*)d_in[12];
    const float* fc1  = (const float*)d_in[13];
    const float* fc1b = (const float*)d_in[14];
    const float* fc2  = (const float*)d_in[15];
    const float* fc2b = (const float*)d_in[16];
    float* out = (float*)d_out;
    float* ws  = (float*)d_ws;

    float* bias1  = ws;                              // 1,536 f
    float* bias2s = bias1 + 1536;                    // 512 f
    float* wxbb   = bias2s + 512;                    // 5,324,800 f
    f16* meta2    = (f16*)(wxbb + 5324800);          // BNP*128 = 1,343,488
    f16* B1t      = meta2 + (size_t)BNP * 128;       // 196,608
    f16* hdn_all  = B1t + 196608;                    // BNP*1536
    f16* b2t      = hdn_all + (size_t)BNP * 1536;    // 4*4096*128
    f16* b2s      = b2t + (size_t)4 * 4096 * 128;    // 65,536
    f16* whbuf    = b2s + 65536;                     // chunk*16384

    const size_t fixedB = (size_t)(1536 + 512 + 5324800) * 4
        + ((size_t)BNP * 128 + 196608 + (size_t)BNP * 1536
           + (size_t)4 * 4096 * 128 + 65536) * 2;
    size_t availB = (ws_size > fixedB) ? (ws_size - fixedB) : 0;
    long long ch = (long long)(availB / (16384 * 2));
    if (ch > 5248) ch = 5248;
    if (ch < 128)  ch = 128;
    int chunk = (int)(ch & ~127LL);

    meta2_kernel<<<(BNP * 128 + 255) / 256, 256, 0, stream>>>(x, meta2);
    prep_b2t_kernel<<<1544, 256, 0, stream>>>(wx1, wx1b, wx2, wx2b, wh1, wh1b,
                                              b1, b1b, b2, b2b, wh2,
                                              B1t, bias1, b2s, bias2s, b2t);
    stage1_gemm<<<dim3(12, BNP / 128), 256, 0, stream>>>(meta2, B1t, bias1, hdn_all);
    stage2s_gemm<<<dim3(BNP / 128, 8), 256, 0, stream>>>(hdn_all, b2s, bias2s, wxbb);
    for (int c0 = 0; c0 < BN; c0 += chunk) {
        int cr = BN - c0;
        if (cr > chunk) cr = chunk;
        gemm_wh_mfma<<<dim3(32, (cr + 127) / 128, 4), 256, 0, stream>>>(
            hdn_all, b2t, wh2b, whbuf, c0, cr);
        lstm_head_kernel<<<(cr + 3) / 4, 256, 0, stream>>>(whbuf, wxbb, x, fc1, fc1b,
                                                           fc2, fc2b, out, c0, cr);
    }
}